// Round 1
// baseline (658.582 us; speedup 1.0000x reference)
//
#include <hip/hip_runtime.h>
#include <hip/hip_bf16.h>

#define N_B   4
#define C_IN  128
#define HH    64
#define WW    64
#define HWSZ  4096
#define C_M   256
#define UPF   16

// ---------------------------------------------------------------------------
// Generic 3x3 conv (pad=1), LDS-staged input, CO_T output channels per block.
// Block = 256 threads = 64w x 4h. Grid = (16 h-tiles, cout/CO_T, N).
// ---------------------------------------------------------------------------
template<int CO_T>
__global__ void __launch_bounds__(256)
conv3x3_stage(const float* __restrict__ img,
              const float* __restrict__ w,
              const float* __restrict__ bias,
              float* __restrict__ out,
              int cout)
{
    __shared__ float s_img[16][6][66];   // 16 ch x (4+2 halo rows) x (64+2 cols)

    const int n   = blockIdx.z;
    const int h0  = blockIdx.x * 4;
    const int co0 = blockIdx.y * CO_T;
    const int tx  = threadIdx.x & 63;    // w
    const int ty  = threadIdx.x >> 6;    // local h

    float acc[CO_T];
#pragma unroll
    for (int co = 0; co < CO_T; ++co) acc[co] = bias[co0 + co];

    for (int cc = 0; cc < C_IN; cc += 16) {
        __syncthreads();
        for (int idx = threadIdx.x; idx < 16 * 6 * 66; idx += 256) {
            int c   = idx / 396;
            int rem = idx - c * 396;
            int r   = rem / 66;
            int col = rem - r * 66;
            int gy = h0 - 1 + r;
            int gx = col - 1;
            float v = 0.f;
            if ((unsigned)gy < 64u && (unsigned)gx < 64u)
                v = img[((n * C_IN + cc + c) * HH + gy) * WW + gx];
            s_img[c][r][col] = v;
        }
        __syncthreads();
#pragma unroll 2
        for (int c = 0; c < 16; ++c) {
            float t[9];
#pragma unroll
            for (int dy = 0; dy < 3; ++dy)
#pragma unroll
                for (int dx = 0; dx < 3; ++dx)
                    t[dy * 3 + dx] = s_img[c][ty + dy][tx + dx];
            const float* wp = &w[((co0) * C_IN + cc + c) * 9];
#pragma unroll
            for (int co = 0; co < CO_T; ++co) {
                const float* wq = wp + co * C_IN * 9;   // block-uniform -> s_load
                acc[co] += wq[0] * t[0] + wq[1] * t[1] + wq[2] * t[2]
                         + wq[3] * t[3] + wq[4] * t[4] + wq[5] * t[5]
                         + wq[6] * t[6] + wq[7] * t[7] + wq[8] * t[8];
            }
        }
    }
#pragma unroll
    for (int co = 0; co < CO_T; ++co)
        out[((n * cout + co0 + co) * HH + h0 + ty) * WW + tx] = acc[co];
}

// ---------------------------------------------------------------------------
// BN batch stats per channel -> affine (a, b): bn(x) = a*x + b.
// One block per channel; reduces over N*H*W = 16384 values.
// ---------------------------------------------------------------------------
__global__ void __launch_bounds__(256)
bn_stats(const float* __restrict__ x,
         const float* __restrict__ gamma,
         const float* __restrict__ beta,
         float* __restrict__ ab, int C)
{
    const int c = blockIdx.x;
    float s = 0.f, s2 = 0.f;
    for (int n = 0; n < N_B; ++n) {
        const float* p = x + (size_t)(n * C + c) * HWSZ;
        for (int i = threadIdx.x; i < HWSZ; i += 256) {
            float v = p[i];
            s += v; s2 += v * v;
        }
    }
#pragma unroll
    for (int off = 32; off > 0; off >>= 1) {
        s  += __shfl_down(s,  off, 64);
        s2 += __shfl_down(s2, off, 64);
    }
    __shared__ float rs[4], rs2[4];
    const int wid = threadIdx.x >> 6, lane = threadIdx.x & 63;
    if (lane == 0) { rs[wid] = s; rs2[wid] = s2; }
    __syncthreads();
    if (threadIdx.x == 0) {
        float S  = rs[0] + rs[1] + rs[2] + rs[3];
        float S2 = rs2[0] + rs2[1] + rs2[2] + rs2[3];
        const float inv = 1.0f / (float)(N_B * HWSZ);
        float mu  = S * inv;
        float var = S2 * inv - mu * mu;      // population var (ddof=0)
        float r   = rsqrtf(var + 1e-5f);
        float a   = gamma[c] * r;
        ab[2 * c]     = a;
        ab[2 * c + 1] = beta[c] - mu * a;
    }
}

// ---------------------------------------------------------------------------
// Second flow conv: flow8 = 8 * (conv3x3(relu(bn(h_pre)), fh_w2) + fh_b2)
// One thread per output element (tiny: 32768 outputs).
// ---------------------------------------------------------------------------
__global__ void __launch_bounds__(256)
flow_conv2(const float* __restrict__ hpre,
           const float* __restrict__ ab,
           const float* __restrict__ w2,    // (2,2,3,3)
           const float* __restrict__ b2,
           float* __restrict__ flow8)
{
    int idx = blockIdx.x * 256 + threadIdx.x;     // (n,co,h,w) flat
    int w  = idx & 63;
    int h  = (idx >> 6) & 63;
    int co = (idx >> 12) & 1;
    int n  = idx >> 13;
    float acc = b2[co];
#pragma unroll
    for (int ci = 0; ci < 2; ++ci) {
        float a = ab[2 * ci], b = ab[2 * ci + 1];
        const float* p  = hpre + (size_t)(n * 2 + ci) * HWSZ;
        const float* wp = &w2[(co * 2 + ci) * 9];
#pragma unroll
        for (int dy = 0; dy < 3; ++dy) {
#pragma unroll
            for (int dx = 0; dx < 3; ++dx) {
                int gy = h + dy - 1, gx = w + dx - 1;
                float v = 0.f;
                if ((unsigned)gy < 64u && (unsigned)gx < 64u)
                    v = fmaxf(a * p[gy * 64 + gx] + b, 0.f);
                acc += wp[dy * 3 + dx] * v;
            }
        }
    }
    flow8[idx] = acc * 8.0f;    // pre-multiply by 8 (unfold(8*flow))
}

// ---------------------------------------------------------------------------
// Fused: 1x1 conv (256->2304) + bias + *0.25 + softmax over k(9) + convex
// combine with unfolded flow + transposed write. Mask tensor never hits HBM.
// Block: 256 thr = 16 uv x 16 pixel-groups(8 px). Tile: 16 uv x 2 rows(128 px).
// Grid = (32 row-pairs, 16 uv-tiles, N).
// ---------------------------------------------------------------------------
__global__ void __launch_bounds__(256)
mask_combine(const float* __restrict__ m_pre,   // (4,256,4096)
             const float* __restrict__ ab,      // (256,2)
             const float* __restrict__ w2,      // (2304,256)
             const float* __restrict__ b2,      // (2304)
             const float* __restrict__ flow8,   // (4,2,4096), already *8
             float* __restrict__ out)           // (4,2,1024,1024)
{
    __shared__ float s_m[64][128];     // [k-chunk chan][2-row pixels] 32 KB
    __shared__ float s_w[9][16][68];   // [k][uv-local][kk] (+pad)     38.25 KB
    __shared__ float s_fl[2][4][66];   // flow rows h0-1..h0+2, col-padded

    const int h0  = blockIdx.x * 2;
    const int uv0 = blockIdx.y * 16;
    const int n   = blockIdx.z;
    const int tid = threadIdx.x;
    const int ul  = tid >> 4;          // local uv 0..15
    const int hwb = (tid & 15) * 8;    // pixel base 0..120 (8 per thread)
    const int uv  = uv0 + ul;
    const int u   = uv >> 4, v = uv & 15;

    // stage flow rows (zero-padded halo)
    for (int idx = tid; idx < 2 * 4 * 66; idx += 256) {
        int c   = idx / 264;
        int rem = idx - c * 264;
        int r   = rem / 66;
        int col = rem - r * 66;
        int gy = h0 - 1 + r, gx = col - 1;
        float vv = 0.f;
        if ((unsigned)gy < 64u && (unsigned)gx < 64u)
            vv = flow8[(size_t)(n * 2 + c) * HWSZ + gy * WW + gx];
        s_fl[c][r][col] = vv;
    }

    float acc[9][8];
#pragma unroll
    for (int k = 0; k < 9; ++k)
#pragma unroll
        for (int j = 0; j < 8; ++j) acc[k][j] = 0.f;

    for (int kc = 0; kc < 4; ++kc) {
        const int cb = kc * 64;
        __syncthreads();
        // stage m chunk with BN + ReLU fused
        for (int idx = tid; idx < 64 * 128; idx += 256) {
            int r = idx >> 7;
            int p = idx & 127;
            int c = cb + r;
            float a = ab[2 * c], b = ab[2 * c + 1];
            float x = m_pre[((size_t)(n * C_M + c)) * HWSZ + h0 * WW + p];
            s_m[r][p] = fmaxf(a * x + b, 0.f);
        }
        // stage w2 chunk (144 rows x 64 kk)
        for (int idx = tid; idx < 144 * 64; idx += 256) {
            int row = idx >> 6;
            int kk  = idx & 63;
            int k  = row >> 4, u2 = row & 15;
            s_w[k][u2][kk] = w2[(size_t)(k * 256 + uv0 + u2) * 256 + cb + kk];
        }
        __syncthreads();

        for (int kk = 0; kk < 64; kk += 4) {
            float4 ma[4], mb[4];
#pragma unroll
            for (int q = 0; q < 4; ++q) {
                ma[q] = *(const float4*)&s_m[kk + q][hwb];
                mb[q] = *(const float4*)&s_m[kk + q][hwb + 4];
            }
#pragma unroll
            for (int k = 0; k < 9; ++k) {
                float4 wv = *(const float4*)&s_w[k][ul][kk];
                float wf[4] = {wv.x, wv.y, wv.z, wv.w};
#pragma unroll
                for (int q = 0; q < 4; ++q) {
                    acc[k][0] += wf[q] * ma[q].x;
                    acc[k][1] += wf[q] * ma[q].y;
                    acc[k][2] += wf[q] * ma[q].z;
                    acc[k][3] += wf[q] * ma[q].w;
                    acc[k][4] += wf[q] * mb[q].x;
                    acc[k][5] += wf[q] * mb[q].y;
                    acc[k][6] += wf[q] * mb[q].z;
                    acc[k][7] += wf[q] * mb[q].w;
                }
            }
        }
    }

    // epilogue: bias + 0.25 + softmax(k) + flow combine + transposed store
    const int hl    = hwb >> 6;          // 0/1 row within pair
    const int wbase = hwb & 63;
    const int h     = h0 + hl;
    float bk[9];
#pragma unroll
    for (int k = 0; k < 9; ++k) bk[k] = b2[k * 256 + uv];

#pragma unroll
    for (int j = 0; j < 8; ++j) {
        const int w = wbase + j;
        float p[9], mx = -1e30f;
#pragma unroll
        for (int k = 0; k < 9; ++k) {
            p[k] = (acc[k][j] + bk[k]) * 0.25f;
            mx = fmaxf(mx, p[k]);
        }
        float s = 0.f;
#pragma unroll
        for (int k = 0; k < 9; ++k) { p[k] = __expf(p[k] - mx); s += p[k]; }
        float inv = 1.0f / s;
#pragma unroll
        for (int c = 0; c < 2; ++c) {
            float o = 0.f;
#pragma unroll
            for (int k = 0; k < 9; ++k)
                o += p[k] * s_fl[c][hl + (k / 3)][w + (k % 3)];
            out[((size_t)(n * 2 + c) * 1024 + h * UPF + u) * 1024 + w * UPF + v] = o * inv;
        }
    }
}

// ---------------------------------------------------------------------------
extern "C" void kernel_launch(void* const* d_in, const int* in_sizes, int n_in,
                              void* d_out, int out_size, void* d_ws, size_t ws_size,
                              hipStream_t stream) {
    const float* img   = (const float*)d_in[0];
    const float* fh_w1 = (const float*)d_in[1];
    const float* fh_b1 = (const float*)d_in[2];
    const float* fh_g  = (const float*)d_in[3];
    const float* fh_be = (const float*)d_in[4];
    const float* fh_w2 = (const float*)d_in[5];
    const float* fh_b2 = (const float*)d_in[6];
    const float* mk_w1 = (const float*)d_in[7];
    const float* mk_b1 = (const float*)d_in[8];
    const float* mk_g  = (const float*)d_in[9];
    const float* mk_be = (const float*)d_in[10];
    const float* mk_w2 = (const float*)d_in[11];
    const float* mk_b2 = (const float*)d_in[12];
    float* out = (float*)d_out;

    float* ws    = (float*)d_ws;
    float* m_pre = ws;                                   // 4*256*4096 = 4194304
    float* h_pre = m_pre + (size_t)N_B * C_M * HWSZ;     // 4*2*4096   = 32768
    float* flow8 = h_pre + (size_t)N_B * 2 * HWSZ;       // 32768
    float* ab_m  = flow8 + (size_t)N_B * 2 * HWSZ;       // 512
    float* ab_h  = ab_m + 512;                           // 4
    // total ~17.05 MB of d_ws

    // flow head conv1 (128->2)
    conv3x3_stage<2><<<dim3(16, 1, 4), 256, 0, stream>>>(img, fh_w1, fh_b1, h_pre, 2);
    // mask head conv1 (128->256) -- the big 3x3 conv
    conv3x3_stage<16><<<dim3(16, 16, 4), 256, 0, stream>>>(img, mk_w1, mk_b1, m_pre, 256);
    // BN stats
    bn_stats<<<2,   256, 0, stream>>>(h_pre, fh_g, fh_be, ab_h, 2);
    bn_stats<<<256, 256, 0, stream>>>(m_pre, mk_g, mk_be, ab_m, 256);
    // flow head conv2 (+bn+relu on input), pre-scaled by 8
    flow_conv2<<<128, 256, 0, stream>>>(h_pre, ab_h, fh_w2, fh_b2, flow8);
    // fused 1x1 conv + softmax + convex upsample
    mask_combine<<<dim3(32, 16, 4), 256, 0, stream>>>(m_pre, ab_m, mk_w2, mk_b2, flow8, out);
}

// Round 2
// 167.015 us; speedup vs baseline: 3.9433x; 3.9433x over previous
//
#include <hip/hip_runtime.h>
#include <hip/hip_bf16.h>

#define N_B   4
#define C_IN  128
#define HWSZ  4096
#define C_M   256

typedef __attribute__((ext_vector_type(8))) short          s16x8;   // bf16x8 frag (4 VGPR)
typedef __attribute__((ext_vector_type(8))) unsigned short u16x8;
typedef __attribute__((ext_vector_type(4))) float          f32x4;

__device__ __forceinline__ unsigned short f2bf(float f) {
    union { float f; unsigned u; } v; v.f = f;
    unsigned r = v.u + 0x7fffu + ((v.u >> 16) & 1u);   // RNE
    return (unsigned short)(r >> 16);
}
__device__ __forceinline__ float bf2f(unsigned short u) {
    union { unsigned u; float f; } v; v.u = ((unsigned)u) << 16; return v.f;
}

// ---------------------------------------------------------------------------
// Build bf16 weight layouts.
// w1x[cox 0..287][cc 0..3][tap 0..8][ciw 0..31]: cox = z*144+row;
//   row<128 -> mk_w1[z*128+row]; z==0 && row in {128,129} -> fh_w1; else 0.
// w2b[ko 0..2303][c 0..255] = bf16(mk_w2)
// ---------------------------------------------------------------------------
__global__ void __launch_bounds__(256)
prep_weights(const float* __restrict__ mk_w1, const float* __restrict__ fh_w1,
             const float* __restrict__ mk_w2,
             unsigned short* __restrict__ w1x, unsigned short* __restrict__ w2b)
{
    int i = blockIdx.x * 256 + threadIdx.x;
    if (i < 2304 * 256) w2b[i] = f2bf(mk_w2[i]);
    if (i < 288 * 1152) {
        int cox = i / 1152;
        int rem = i - cox * 1152;
        int cc  = rem / 288;
        int r2  = rem - cc * 288;
        int tap = r2 >> 5;
        int ciw = r2 & 31;
        int ci  = cc * 32 + ciw;
        int z = cox / 144, row = cox - z * 144;
        float w = 0.f;
        if (row < 128)                    w = mk_w1[((z * 128 + row) * C_IN + ci) * 9 + tap];
        else if (z == 0 && row < 130)     w = fh_w1[((row - 128) * C_IN + ci) * 9 + tap];
        w1x[i] = f2bf(w);
    }
}

// ---------------------------------------------------------------------------
// img (n,ci,h,w) fp32 -> imgT (n,h,w,ci) bf16 via LDS tile transpose.
// ---------------------------------------------------------------------------
__global__ void __launch_bounds__(256)
img_transpose(const float* __restrict__ img, unsigned short* __restrict__ imgT)
{
    __shared__ float s[128][65];
    const int n = blockIdx.y, h = blockIdx.x;
    const float* src = img + (size_t)n * C_IN * HWSZ + h * 64;
    for (int i = threadIdx.x; i < 128 * 64; i += 256) {
        int ci = i >> 6, w = i & 63;
        s[ci][w] = src[(size_t)ci * HWSZ + w];
    }
    __syncthreads();
    unsigned short* dst = imgT + ((size_t)(n * 64 + h) * 64) * 128;
    for (int i = threadIdx.x; i < 64 * 128; i += 256) {
        int w = i >> 7, ci = i & 127;
        dst[(size_t)w * 128 + ci] = f2bf(s[ci][w]);
    }
}

// ---------------------------------------------------------------------------
// MFMA implicit-GEMM 3x3 conv, pad=1. M=144 rows (128 mask co + 2 flow co +
// 14 pad), K=1152 (4 ci-chunks x 9 taps x 32 ci), N=128 px (2 image rows).
// 512 thr (8 waves x 16 px). grid (32 rowpairs, 4 n, 2 cotiles).
// Outputs: m_bf (bf16, with bias), h_pre (fp32, cotile 0 only).
// ---------------------------------------------------------------------------
__global__ void __launch_bounds__(512)
conv1_mfma(const unsigned short* __restrict__ imgT,
           const unsigned short* __restrict__ w1x,
           const float* __restrict__ mk_b1, const float* __restrict__ fh_b1,
           unsigned short* __restrict__ m_bf, float* __restrict__ h_pre)
{
    __shared__ unsigned short s_w[9][144][40];   // 103,680 B (per ci-chunk)
    __shared__ unsigned short s_img[4][66][40];  //  21,120 B
    __shared__ float s_bias[144];

    const int h0 = blockIdx.x * 2;
    const int n  = blockIdx.y;
    const int z  = blockIdx.z;
    const int tid = threadIdx.x;
    const int wv = tid >> 6, lane = tid & 63;
    const int lg = lane >> 4, ln = lane & 15;
    const int rowsel = wv >> 2;          // image row within pair
    const int wpx = (wv & 3) * 16 + ln;  // w coordinate 0..63
    const int h = h0 + rowsel;

    if (tid < 144) {
        float b = 0.f;
        if (tid < 128)                 b = mk_b1[z * 128 + tid];
        else if (z == 0 && tid < 130)  b = fh_b1[tid - 128];
        s_bias[tid] = b;
    }

    f32x4 acc[9];
#pragma unroll
    for (int g = 0; g < 9; ++g) acc[g] = (f32x4){0.f, 0.f, 0.f, 0.f};

    for (int cc = 0; cc < 4; ++cc) {
        __syncthreads();
        // stage image chunk: rows h0-1..h0+2, cols -1..64, 32 ci (bf16)
        for (int i = tid; i < 4 * 66 * 4; i += 512) {
            int r = i / 264;
            int rem = i - r * 264;
            int c = rem >> 2, hf = rem & 3;
            int gy = h0 - 1 + r, gx = c - 1;
            u16x8 v = {0, 0, 0, 0, 0, 0, 0, 0};
            if ((unsigned)gy < 64u && (unsigned)gx < 64u)
                v = *(const u16x8*)&imgT[((size_t)((n * 64 + gy) * 64 + gx)) * 128 + cc * 32 + hf * 8];
            *(u16x8*)&s_img[r][c][hf * 8] = v;
        }
        // stage weight chunk: [tap][row 0..143][32 ci]
        for (int i = tid; i < 144 * 36; i += 512) {
            int row = i / 36;
            int rem = i - row * 36;
            int tap = rem >> 2, hf = rem & 3;
            u16x8 v = *(const u16x8*)&w1x[(((size_t)((z * 144 + row) * 4 + cc) * 9) + tap) * 32 + hf * 8];
            *(u16x8*)&s_w[tap][row][hf * 8] = v;
        }
        __syncthreads();

#pragma unroll
        for (int tap = 0; tap < 9; ++tap) {
            const int dy = tap / 3, dx = tap % 3;
            s16x8 bf = *(const s16x8*)&s_img[rowsel + dy][wpx + dx][lg * 8];
#pragma unroll
            for (int g = 0; g < 9; ++g) {
                s16x8 af = *(const s16x8*)&s_w[tap][g * 16 + ln][lg * 8];
                acc[g] = __builtin_amdgcn_mfma_f32_16x16x32_bf16(af, bf, acc[g], 0, 0, 0);
            }
        }
    }

    const int px = h * 64 + wpx;
#pragma unroll
    for (int g = 0; g < 9; ++g) {
#pragma unroll
        for (int r = 0; r < 4; ++r) {
            int row = g * 16 + lg * 4 + r;
            float v = acc[g][r] + s_bias[row];
            if (row < 128)
                m_bf[((size_t)(n * C_M + z * 128 + row)) * HWSZ + px] = f2bf(v);
            else if (z == 0 && row < 130)
                h_pre[((size_t)(n * 2 + (row - 128))) * HWSZ + px] = v;
        }
    }
}

// ---------------------------------------------------------------------------
// BN batch stats (fp32 input) -> affine a,b
// ---------------------------------------------------------------------------
__global__ void __launch_bounds__(256)
bn_stats(const float* __restrict__ x, const float* __restrict__ gamma,
         const float* __restrict__ beta, float* __restrict__ ab, int C)
{
    const int c = blockIdx.x;
    float s = 0.f, s2 = 0.f;
    for (int n = 0; n < N_B; ++n) {
        const float* p = x + (size_t)(n * C + c) * HWSZ;
        for (int i = threadIdx.x; i < HWSZ; i += 256) {
            float v = p[i]; s += v; s2 += v * v;
        }
    }
#pragma unroll
    for (int off = 32; off > 0; off >>= 1) {
        s += __shfl_down(s, off, 64); s2 += __shfl_down(s2, off, 64);
    }
    __shared__ float rs[4], rs2[4];
    const int wid = threadIdx.x >> 6, lane = threadIdx.x & 63;
    if (lane == 0) { rs[wid] = s; rs2[wid] = s2; }
    __syncthreads();
    if (threadIdx.x == 0) {
        float S = rs[0] + rs[1] + rs[2] + rs[3];
        float S2 = rs2[0] + rs2[1] + rs2[2] + rs2[3];
        const float inv = 1.0f / (float)(N_B * HWSZ);
        float mu = S * inv;
        float var = S2 * inv - mu * mu;
        float r = rsqrtf(var + 1e-5f);
        float a = gamma[c] * r;
        ab[2 * c] = a; ab[2 * c + 1] = beta[c] - mu * a;
    }
}

// bf16-input variant
__global__ void __launch_bounds__(256)
bn_stats_bf(const unsigned short* __restrict__ x, const float* __restrict__ gamma,
            const float* __restrict__ beta, float* __restrict__ ab, int C)
{
    const int c = blockIdx.x;
    float s = 0.f, s2 = 0.f;
    for (int n = 0; n < N_B; ++n) {
        const unsigned short* p = x + (size_t)(n * C + c) * HWSZ;
        for (int i = threadIdx.x; i < HWSZ; i += 256) {
            float v = bf2f(p[i]); s += v; s2 += v * v;
        }
    }
#pragma unroll
    for (int off = 32; off > 0; off >>= 1) {
        s += __shfl_down(s, off, 64); s2 += __shfl_down(s2, off, 64);
    }
    __shared__ float rs[4], rs2[4];
    const int wid = threadIdx.x >> 6, lane = threadIdx.x & 63;
    if (lane == 0) { rs[wid] = s; rs2[wid] = s2; }
    __syncthreads();
    if (threadIdx.x == 0) {
        float S = rs[0] + rs[1] + rs[2] + rs[3];
        float S2 = rs2[0] + rs2[1] + rs2[2] + rs2[3];
        const float inv = 1.0f / (float)(N_B * HWSZ);
        float mu = S * inv;
        float var = S2 * inv - mu * mu;
        float r = rsqrtf(var + 1e-5f);
        float a = gamma[c] * r;
        ab[2 * c] = a; ab[2 * c + 1] = beta[c] - mu * a;
    }
}

// ---------------------------------------------------------------------------
// m_bf (n,c,px) bf16 -> m_bfT (n,px,c) bf16 with BN+ReLU applied.
// ---------------------------------------------------------------------------
__global__ void __launch_bounds__(256)
bnrelu_transpose(const unsigned short* __restrict__ m_bf, const float* __restrict__ ab,
                 unsigned short* __restrict__ m_bfT)
{
    __shared__ float s[256][65];   // 66,560 B
    const int n = blockIdx.y, hrow = blockIdx.x;
    const unsigned short* src = m_bf + (size_t)n * C_M * HWSZ + hrow * 64;
    for (int i = threadIdx.x; i < 256 * 64; i += 256) {
        int c = i >> 6, w = i & 63;
        float a = ab[2 * c], b = ab[2 * c + 1];
        s[c][w] = fmaxf(a * bf2f(src[(size_t)c * HWSZ + w]) + b, 0.f);
    }
    __syncthreads();
    unsigned short* dst = m_bfT + ((size_t)(n * HWSZ + hrow * 64)) * 256;
    for (int i = threadIdx.x; i < 64 * 256; i += 256) {
        int w = i >> 8, c = i & 255;
        dst[(size_t)w * 256 + c] = f2bf(s[c][w]);
    }
}

// ---------------------------------------------------------------------------
// flow8 = 8 * (conv3x3(relu(bn(h_pre)), fh_w2) + fh_b2)   (fp32, tiny)
// ---------------------------------------------------------------------------
__global__ void __launch_bounds__(256)
flow_conv2(const float* __restrict__ hpre, const float* __restrict__ ab,
           const float* __restrict__ w2, const float* __restrict__ b2,
           float* __restrict__ flow8)
{
    int idx = blockIdx.x * 256 + threadIdx.x;
    int w = idx & 63, h = (idx >> 6) & 63, co = (idx >> 12) & 1, n = idx >> 13;
    float acc = b2[co];
#pragma unroll
    for (int ci = 0; ci < 2; ++ci) {
        float a = ab[2 * ci], b = ab[2 * ci + 1];
        const float* p = hpre + (size_t)(n * 2 + ci) * HWSZ;
        const float* wp = &w2[(co * 2 + ci) * 9];
#pragma unroll
        for (int dy = 0; dy < 3; ++dy)
#pragma unroll
            for (int dx = 0; dx < 3; ++dx) {
                int gy = h + dy - 1, gx = w + dx - 1;
                float v = 0.f;
                if ((unsigned)gy < 64u && (unsigned)gx < 64u)
                    v = fmaxf(a * p[gy * 64 + gx] + b, 0.f);
                acc += wp[dy * 3 + dx] * v;
            }
    }
    flow8[idx] = acc * 8.0f;
}

// ---------------------------------------------------------------------------
// MFMA 1x1-conv GEMM (W 2304x256 x M 256xpx) + bias + softmax(9) + convex
// upsample, transposed coalesced store. Block owns 16 uv x 8 image rows;
// W-tile staged once. 256 thr (4 waves x 16 px). grid (8 hgrp, 16 uvt, 4 n).
// ---------------------------------------------------------------------------
__global__ void __launch_bounds__(256)
mask_combine_mfma(const unsigned short* __restrict__ m_bfT,
                  const unsigned short* __restrict__ w2b,
                  const float* __restrict__ mk_b2,
                  const float* __restrict__ flow8,
                  float* __restrict__ out)
{
    __shared__ unsigned short s_w[9][16][264];   // 76,032 B
    __shared__ float s_fl[2][3][66];
    __shared__ float s_out[2][1024];

    const int hg = blockIdx.x, uv0 = blockIdx.y * 16, n = blockIdx.z;
    const int u = uv0 >> 4;
    const int tid = threadIdx.x, wv = tid >> 6, lane = tid & 63;
    const int lg = lane >> 4, ln = lane & 15;
    const int wpx = wv * 16 + ln;      // w 0..63

    // stage W tile once: 144 rows x 256 c
    for (int i = tid; i < 144 * 32; i += 256) {
        int row = i >> 5, hf = i & 31;
        int k = row >> 4, r = row & 15;
        u16x8 v = *(const u16x8*)&w2b[((size_t)(k * 256 + uv0 + r)) * 256 + hf * 8];
        *(u16x8*)&s_w[k][r][hf * 8] = v;
    }

    for (int it = 0; it < 8; ++it) {
        const int h = hg * 8 + it;
        // stage flow halo rows h-1..h+1
        for (int i = tid; i < 2 * 3 * 66; i += 256) {
            int c = i / 198, rem = i - c * 198, r = rem / 66, col = rem - r * 66;
            int gy = h - 1 + r, gx = col - 1;
            float v = 0.f;
            if ((unsigned)gy < 64u && (unsigned)gx < 64u)
                v = flow8[((size_t)(n * 2 + c)) * HWSZ + gy * 64 + gx];
            s_fl[c][r][col] = v;
        }
        __syncthreads();

        f32x4 acc[9];
#pragma unroll
        for (int k = 0; k < 9; ++k) acc[k] = (f32x4){0.f, 0.f, 0.f, 0.f};

        const unsigned short* bptr = &m_bfT[((size_t)(n * HWSZ + h * 64 + wpx)) * 256];
#pragma unroll
        for (int ks = 0; ks < 8; ++ks) {
            s16x8 bf = *(const s16x8*)&bptr[ks * 32 + lg * 8];
#pragma unroll
            for (int k = 0; k < 9; ++k) {
                s16x8 af = *(const s16x8*)&s_w[k][ln][ks * 32 + lg * 8];
                acc[k] = __builtin_amdgcn_mfma_f32_16x16x32_bf16(af, bf, acc[k], 0, 0, 0);
            }
        }

        // epilogue: bias + 0.25 + softmax + combine
#pragma unroll
        for (int r = 0; r < 4; ++r) {
            int v = lg * 4 + r;
            int uv = uv0 + v;
            float p[9], mx = -1e30f;
#pragma unroll
            for (int k = 0; k < 9; ++k) {
                p[k] = (acc[k][r] + mk_b2[k * 256 + uv]) * 0.25f;
                mx = fmaxf(mx, p[k]);
            }
            float sum = 0.f;
#pragma unroll
            for (int k = 0; k < 9; ++k) { p[k] = __expf(p[k] - mx); sum += p[k]; }
            float inv = 1.0f / sum;
            float o0 = 0.f, o1 = 0.f;
#pragma unroll
            for (int k = 0; k < 9; ++k) {
                int dy = k / 3, dx = k % 3;
                o0 += p[k] * s_fl[0][dy][wpx + dx];
                o1 += p[k] * s_fl[1][dy][wpx + dx];
            }
            s_out[0][wpx * 16 + v] = o0 * inv;
            s_out[1][wpx * 16 + v] = o1 * inv;
        }
        __syncthreads();
        // coalesced store: 2 full output rows of 1024
        for (int i = tid; i < 2048; i += 256) {
            int c = i >> 10, col = i & 1023;
            out[((size_t)(n * 2 + c) * 1024 + (h * 16 + u)) * 1024 + col] = s_out[c][col];
        }
    }
}

// ---------------------------------------------------------------------------
extern "C" void kernel_launch(void* const* d_in, const int* in_sizes, int n_in,
                              void* d_out, int out_size, void* d_ws, size_t ws_size,
                              hipStream_t stream) {
    const float* img   = (const float*)d_in[0];
    const float* fh_w1 = (const float*)d_in[1];
    const float* fh_b1 = (const float*)d_in[2];
    const float* fh_g  = (const float*)d_in[3];
    const float* fh_be = (const float*)d_in[4];
    const float* fh_w2 = (const float*)d_in[5];
    const float* fh_b2 = (const float*)d_in[6];
    const float* mk_w1 = (const float*)d_in[7];
    const float* mk_b1 = (const float*)d_in[8];
    const float* mk_g  = (const float*)d_in[9];
    const float* mk_be = (const float*)d_in[10];
    const float* mk_w2 = (const float*)d_in[11];
    const float* mk_b2 = (const float*)d_in[12];
    float* out = (float*)d_out;

    char* p = (char*)d_ws;
    unsigned short* w2b   = (unsigned short*)p;  p += (size_t)2304 * 256 * 2;   // 1,179,648
    unsigned short* w1x   = (unsigned short*)p;  p += (size_t)288 * 1152 * 2;   //   663,552
    unsigned short* imgT  = (unsigned short*)p;                                  // shares region
    unsigned short* m_bfT = (unsigned short*)p;  p += (size_t)8388608;           // lifetimes disjoint
    unsigned short* m_bf  = (unsigned short*)p;  p += (size_t)8388608;
    float* h_pre = (float*)p;                    p += (size_t)131072;
    float* flow8 = (float*)p;                    p += (size_t)131072;
    float* ab_m  = (float*)p;                    p += 2048;
    float* ab_h  = (float*)p;                    p += 64;

    prep_weights<<<2304, 256, 0, stream>>>(mk_w1, fh_w1, mk_w2, w1x, w2b);
    img_transpose<<<dim3(64, 4), 256, 0, stream>>>(img, imgT);
    conv1_mfma<<<dim3(32, 4, 2), 512, 0, stream>>>(imgT, w1x, mk_b1, fh_b1, m_bf, h_pre);
    bn_stats<<<2, 256, 0, stream>>>(h_pre, fh_g, fh_be, ab_h, 2);
    bn_stats_bf<<<256, 256, 0, stream>>>(m_bf, mk_g, mk_be, ab_m, 256);
    flow_conv2<<<128, 256, 0, stream>>>(h_pre, ab_h, fh_w2, fh_b2, flow8);
    bnrelu_transpose<<<dim3(64, 4), 256, 0, stream>>>(m_bf, ab_m, m_bfT);
    mask_combine_mfma<<<dim3(8, 16, 4), 256, 0, stream>>>(m_bfT, w2b, mk_b2, flow8, out);
}

// Round 3
// 122.932 us; speedup vs baseline: 5.3573x; 1.3586x over previous
//
#include <hip/hip_runtime.h>
#include <hip/hip_bf16.h>

#define N_B   4
#define C_IN  128
#define HWSZ  4096
#define C_M   256

typedef __attribute__((ext_vector_type(8))) short          s16x8;   // bf16x8 frag (4 VGPR)
typedef __attribute__((ext_vector_type(8))) unsigned short u16x8;
typedef __attribute__((ext_vector_type(4))) unsigned short u16x4;
typedef __attribute__((ext_vector_type(4))) float          f32x4;

__device__ __forceinline__ unsigned short f2bf(float f) {
    union { float f; unsigned u; } v; v.f = f;
    unsigned r = v.u + 0x7fffu + ((v.u >> 16) & 1u);   // RNE
    return (unsigned short)(r >> 16);
}
__device__ __forceinline__ float bf2f(unsigned short u) {
    union { unsigned u; float f; } v; v.u = ((unsigned)u) << 16; return v.f;
}

// ---------------------------------------------------------------------------
// Fragment-ordered weights.
// w1f: [z2][cc4][tap9][g9][lane64][j8] ; elem = W1(co = z*128?.. see below)
//      co_local = g*16 + (lane>>4)*?? -> A-row = lane&15 within 16-row tile:
//      value = row (g*16 + ln), ci = cc*32 + lg*8 + j, tap.
//      z0 rows 0..127 = mk co 0..127; rows 128,129 = fh co 0,1; else 0.
//      z1 rows 0..127 = mk co 128..255; else 0.
// w2f: [uvt16][k9][ks8][lg4][ln16][j8]; value = mk_w2[(k*256+uvt*16+ln)*256 + ks*32+lg*8+j]
// ---------------------------------------------------------------------------
__global__ void __launch_bounds__(256)
prep_weights(const float* __restrict__ mk_w1, const float* __restrict__ fh_w1,
             const float* __restrict__ mk_w2,
             unsigned short* __restrict__ w1f, unsigned short* __restrict__ w2f)
{
    int i = blockIdx.x * 256 + threadIdx.x;
    if (i < 2304 * 256) {
        int uvt = i / 36864;
        int r   = i - uvt * 36864;
        int k   = r / 4096;
        int r2  = r - k * 4096;
        int ks  = r2 >> 9;
        int lg  = (r2 >> 7) & 3;
        int ln  = (r2 >> 3) & 15;
        int j   = r2 & 7;
        w2f[i] = f2bf(mk_w2[(size_t)(k * 256 + uvt * 16 + ln) * 256 + ks * 32 + lg * 8 + j]);
    }
    if (i < 2 * 4 * 9 * 9 * 512) {
        int z   = i / 165888;
        int r   = i - z * 165888;
        int cc  = r / 41472;
        int r2  = r - cc * 41472;
        int tap = r2 / 4608;
        int r3  = r2 - tap * 4608;
        int g   = r3 / 512;
        int r4  = r3 - g * 512;
        int lane = r4 >> 3, j = r4 & 7;
        int lg = lane >> 4, ln = lane & 15;
        int row = g * 16 + ln;
        int ci  = cc * 32 + lg * 8 + j;
        float w = 0.f;
        if (z == 0) {
            if (row < 128)      w = mk_w1[((size_t)row * C_IN + ci) * 9 + tap];
            else if (row < 130) w = fh_w1[((size_t)(row - 128) * C_IN + ci) * 9 + tap];
        } else {
            if (row < 128)      w = mk_w1[((size_t)(128 + row) * C_IN + ci) * 9 + tap];
        }
        w1f[i] = f2bf(w);
    }
}

// ---------------------------------------------------------------------------
// img (n,ci,h,w) fp32 -> imgT (n,h,w,ci) bf16 via LDS tile transpose.
// ---------------------------------------------------------------------------
__global__ void __launch_bounds__(256)
img_transpose(const float* __restrict__ img, unsigned short* __restrict__ imgT)
{
    __shared__ float s[128][65];
    const int n = blockIdx.y, h = blockIdx.x;
    const float* src = img + (size_t)n * C_IN * HWSZ + h * 64;
    for (int i = threadIdx.x; i < 128 * 64; i += 256) {
        int ci = i >> 6, w = i & 63;
        s[ci][w] = src[(size_t)ci * HWSZ + w];
    }
    __syncthreads();
    unsigned short* dst = imgT + ((size_t)(n * 64 + h) * 64) * 128;
    for (int i = threadIdx.x; i < 64 * 128; i += 256) {
        int w = i >> 7, ci = i & 127;
        dst[(size_t)w * 128 + ci] = f2bf(s[ci][w]);
    }
}

// ---------------------------------------------------------------------------
// conv1: implicit-GEMM 3x3 conv over both heads. One block per image row.
// 512 thr = 8 waves = (z2, half2, gh2); wave: q=2 px-groups x gn g-tiles.
// af streamed from L2 (fragment-ordered w1f), img staged in LDS.
// Writes m_frag (fragment-ordered bf16, biased, pre-BN) and h_pre (fp32).
// m_frag unit: [n][pxg256][ks8][lg4][ln16][j8], c = ks*32+lg*8+j.
// ---------------------------------------------------------------------------
__global__ void __launch_bounds__(512)
conv1_mfma(const unsigned short* __restrict__ imgT,
           const unsigned short* __restrict__ w1f,
           const float* __restrict__ mk_b1, const float* __restrict__ fh_b1,
           unsigned short* __restrict__ m_frag, float* __restrict__ h_pre)
{
    __shared__ unsigned short s_img[3][66][40];   // 15,840 B (pad 40: 80B rows)
    __shared__ float s_bias[2][144];

    const int h = blockIdx.x;       // 0..63
    const int n = blockIdx.y;
    const int tid = threadIdx.x;
    const int wv = tid >> 6, lane = tid & 63;
    const int lg = lane >> 4, ln = lane & 15;
    const int z = wv >> 2, half = (wv >> 1) & 1, gh = wv & 1;
    const int g0 = gh ? (z ? 4 : 5) : 0;
    const int gn = gh ? 4 : (z ? 4 : 5);

    if (tid < 288) {
        int zz = tid / 144, cl = tid - zz * 144;
        float b = 0.f;
        if (zz == 0) {
            if (cl < 128)      b = mk_b1[cl];
            else if (cl < 130) b = fh_b1[cl - 128];
        } else if (cl < 128)   b = mk_b1[128 + cl];
        s_bias[zz][cl] = b;
    }

    f32x4 acc[5][2];
#pragma unroll
    for (int g = 0; g < 5; ++g)
#pragma unroll
        for (int q = 0; q < 2; ++q) acc[g][q] = (f32x4){0.f, 0.f, 0.f, 0.f};

    for (int cc = 0; cc < 4; ++cc) {
        __syncthreads();
        // stage rows h-1..h+1, cols -1..64, 32 ci
        for (int i = tid; i < 3 * 66 * 4; i += 512) {
            int r = i / 264;
            int rem = i - r * 264;
            int c = rem >> 2, un = rem & 3;
            int gy = h - 1 + r, gx = c - 1;
            u16x8 v = {0, 0, 0, 0, 0, 0, 0, 0};
            if ((unsigned)gy < 64u && (unsigned)gx < 64u)
                v = *(const u16x8*)&imgT[((size_t)((n * 64 + gy) * 64 + gx)) * 128 + cc * 32 + un * 8];
            *(u16x8*)&s_img[r][c][un * 8] = v;
        }
        __syncthreads();

        const unsigned short* wfp = w1f + ((size_t)((z * 4 + cc) * 9) * 9) * 512 + lane * 8;
#pragma unroll
        for (int tap = 0; tap < 9; ++tap) {
            const int dy = tap / 3, dx = tap % 3;
            s16x8 bf0 = *(const s16x8*)&s_img[dy][half * 32 + ln + dx][lg * 8];
            s16x8 bf1 = *(const s16x8*)&s_img[dy][half * 32 + 16 + ln + dx][lg * 8];
#pragma unroll
            for (int gi = 0; gi < 5; ++gi) {
                if (gi < gn) {
                    s16x8 af = *(const s16x8*)&wfp[(size_t)(tap * 9 + g0 + gi) * 512];
                    acc[gi][0] = __builtin_amdgcn_mfma_f32_16x16x32_bf16(af, bf0, acc[gi][0], 0, 0, 0);
                    acc[gi][1] = __builtin_amdgcn_mfma_f32_16x16x32_bf16(af, bf1, acc[gi][1], 0, 0, 0);
                }
            }
        }
    }

    // epilogue
#pragma unroll
    for (int gi = 0; gi < 5; ++gi) {
        if (gi >= gn) continue;
        const int g = g0 + gi;
#pragma unroll
        for (int q = 0; q < 2; ++q) {
            const int px  = half * 32 + q * 16 + ln;
            const int pxg = h * 4 + half * 2 + q;
            if (z == 0 && g == 8) {
                if (lg == 0) {
#pragma unroll
                    for (int r = 0; r < 2; ++r)
                        h_pre[((size_t)(n * 2 + r)) * HWSZ + h * 64 + px] =
                            acc[gi][q][r] + s_bias[0][128 + r];
                }
            } else {
                u16x4 vv;
#pragma unroll
                for (int r = 0; r < 4; ++r)
                    vv[r] = f2bf(acc[gi][q][r] + s_bias[z][g * 16 + lg * 4 + r]);
                int ks  = z * 4 + (g >> 1);
                int lgp = ((g & 1) * 2 + (lg >> 1)) & 3;
                size_t off = ((((size_t)(n * 256 + pxg) * 8 + ks) * 4 + lgp) * 128) + ln * 8 + (lg & 1) * 4;
                *(u16x4*)&m_frag[off] = vv;
            }
        }
    }
}

// ---------------------------------------------------------------------------
// BN batch stats, fp32 input (flow head, C=2)
// ---------------------------------------------------------------------------
__global__ void __launch_bounds__(256)
bn_stats(const float* __restrict__ x, const float* __restrict__ gamma,
         const float* __restrict__ beta, float* __restrict__ ab, int C)
{
    const int c = blockIdx.x;
    float s = 0.f, s2 = 0.f;
    for (int n = 0; n < N_B; ++n) {
        const float* p = x + (size_t)(n * C + c) * HWSZ;
        for (int i = threadIdx.x; i < HWSZ; i += 256) {
            float v = p[i]; s += v; s2 += v * v;
        }
    }
#pragma unroll
    for (int off = 32; off > 0; off >>= 1) {
        s += __shfl_down(s, off, 64); s2 += __shfl_down(s2, off, 64);
    }
    __shared__ float rs[4], rs2[4];
    const int wid = threadIdx.x >> 6, lane = threadIdx.x & 63;
    if (lane == 0) { rs[wid] = s; rs2[wid] = s2; }
    __syncthreads();
    if (threadIdx.x == 0) {
        float S = rs[0] + rs[1] + rs[2] + rs[3];
        float S2 = rs2[0] + rs2[1] + rs2[2] + rs2[3];
        const float inv = 1.0f / (float)(N_B * HWSZ);
        float mu = S * inv;
        float var = S2 * inv - mu * mu;
        float r = rsqrtf(var + 1e-5f);
        float a = gamma[c] * r;
        ab[2 * c] = a; ab[2 * c + 1] = beta[c] - mu * a;
    }
}

// ---------------------------------------------------------------------------
// BN stats over m_frag (bf16 fragment order): stage 1 partial sums.
// grid 64 x 256. Thread t owns c-unit class cu=t&31 (ks=cu>>2,lg=cu&3).
// ---------------------------------------------------------------------------
__global__ void __launch_bounds__(256)
bn_partial(const unsigned short* __restrict__ m_frag, float* __restrict__ partial)
{
    __shared__ float red[256][16];
    const int t = threadIdx.x, b = blockIdx.x;
    const int cu = t & 31, ks = cu >> 2, lg = cu & 3;
    float s[8], s2[8];
#pragma unroll
    for (int j = 0; j < 8; ++j) { s[j] = 0.f; s2[j] = 0.f; }
    for (int i = 0; i < 32; ++i) {
        int m = b * 256 + (t >> 5) * 32 + i;     // (n, pxg, ln) combo
        int ln = m & 15, pxg = (m >> 4) & 255, n = m >> 12;
        size_t off = ((((size_t)(n * 256 + pxg) * 8 + ks) * 4 + lg) * 16 + ln) * 8;
        u16x8 v = *(const u16x8*)&m_frag[off];
#pragma unroll
        for (int j = 0; j < 8; ++j) {
            float f = bf2f(v[j]); s[j] += f; s2[j] += f * f;
        }
    }
#pragma unroll
    for (int j = 0; j < 8; ++j) { red[t][j] = s[j]; red[t][8 + j] = s2[j]; }
    __syncthreads();
    // t -> channel c
    {
        int c = t, cuu = c >> 3, j = c & 7;
        float S = 0.f, S2 = 0.f;
#pragma unroll
        for (int w = 0; w < 8; ++w) { S += red[cuu + w * 32][j]; S2 += red[cuu + w * 32][8 + j]; }
        partial[(size_t)(b * 256 + c) * 2] = S;
        partial[(size_t)(b * 256 + c) * 2 + 1] = S2;
    }
}

__global__ void __launch_bounds__(256)
bn_final(const float* __restrict__ partial, const float* __restrict__ gamma,
         const float* __restrict__ beta, float* __restrict__ ab)
{
    int c = threadIdx.x;
    float S = 0.f, S2 = 0.f;
    for (int b = 0; b < 64; ++b) {
        S += partial[(size_t)(b * 256 + c) * 2];
        S2 += partial[(size_t)(b * 256 + c) * 2 + 1];
    }
    const float inv = 1.0f / (float)(N_B * HWSZ);
    float mu = S * inv;
    float var = S2 * inv - mu * mu;
    float r = rsqrtf(var + 1e-5f);
    float a = gamma[c] * r;
    ab[2 * c] = a; ab[2 * c + 1] = beta[c] - mu * a;
}

// ---------------------------------------------------------------------------
// In-place BN+ReLU on m_frag. grid 2048 x 256 (one 16B unit per thread).
// ---------------------------------------------------------------------------
__global__ void __launch_bounds__(256)
bnrelu_frag(unsigned short* __restrict__ m_frag, const float* __restrict__ ab)
{
    __shared__ float s_ab[512];
    const int t = threadIdx.x;
    s_ab[t] = ab[t]; s_ab[256 + t] = ab[256 + t];
    __syncthreads();
    const unsigned u = blockIdx.x * 256 + t;
    const int lg = (u >> 4) & 3, ks = (u >> 7) & 7;
    const int cb = ks * 32 + lg * 8;
    u16x8 v = *(const u16x8*)&m_frag[(size_t)u * 8];
    u16x8 o;
#pragma unroll
    for (int j = 0; j < 8; ++j) {
        float a = s_ab[2 * (cb + j)], b = s_ab[2 * (cb + j) + 1];
        o[j] = f2bf(fmaxf(a * bf2f(v[j]) + b, 0.f));
    }
    *(u16x8*)&m_frag[(size_t)u * 8] = o;
}

// ---------------------------------------------------------------------------
// flow8 = 8 * (conv3x3(relu(bn(h_pre)), fh_w2) + fh_b2)   (fp32, tiny)
// ---------------------------------------------------------------------------
__global__ void __launch_bounds__(256)
flow_conv2(const float* __restrict__ hpre, const float* __restrict__ ab,
           const float* __restrict__ w2, const float* __restrict__ b2,
           float* __restrict__ flow8)
{
    int idx = blockIdx.x * 256 + threadIdx.x;
    int w = idx & 63, h = (idx >> 6) & 63, co = (idx >> 12) & 1, n = idx >> 13;
    float acc = b2[co];
#pragma unroll
    for (int ci = 0; ci < 2; ++ci) {
        float a = ab[2 * ci], b = ab[2 * ci + 1];
        const float* p = hpre + (size_t)(n * 2 + ci) * HWSZ;
        const float* wp = &w2[(co * 2 + ci) * 9];
#pragma unroll
        for (int dy = 0; dy < 3; ++dy)
#pragma unroll
            for (int dx = 0; dx < 3; ++dx) {
                int gy = h + dy - 1, gx = w + dx - 1;
                float v = 0.f;
                if ((unsigned)gy < 64u && (unsigned)gx < 64u)
                    v = fmaxf(a * p[gy * 64 + gx] + b, 0.f);
                acc += wp[dy * 3 + dx] * v;
            }
    }
    flow8[idx] = acc * 8.0f;
}

// ---------------------------------------------------------------------------
// Fused 1x1-conv GEMM + bias + softmax(9) + convex upsample.
// grid (8 hgrp, 16 uvt, 4 n), 512 thr = 8 waves, one image row per wave.
// W tile (fragment-ordered) staged once per block; af reused over 4 px-grps.
// ---------------------------------------------------------------------------
__global__ void __launch_bounds__(512)
mask_combine_mfma(const unsigned short* __restrict__ m_frag,
                  const unsigned short* __restrict__ w2f,
                  const float* __restrict__ mk_b2,
                  const float* __restrict__ flow8,
                  float* __restrict__ out)
{
    __shared__ unsigned short s_w[36864];       // 73,728 B, fragment order
    __shared__ float s_fl[2][10][66];           // 5,280 B
    __shared__ float s_bias[9][16];             // 576 B

    const int hg = blockIdx.x, uvt = blockIdx.y, n = blockIdx.z;
    const int tid = threadIdx.x;
    const int wv = tid >> 6, lane = tid & 63;
    const int lg = lane >> 4, ln = lane & 15;

    // stage W tile (linear copy, conflict-free)
    {
        const u16x8* wsrc = (const u16x8*)(w2f + (size_t)uvt * 36864);
        u16x8* wdst = (u16x8*)s_w;
        for (int i = tid; i < 4608; i += 512) wdst[i] = wsrc[i];
    }
    // stage flow rows hg*8-1 .. hg*8+8
    for (int i = tid; i < 2 * 10 * 66; i += 512) {
        int c = i / 660, rem = i - c * 660, r = rem / 66, col = rem - r * 66;
        int gy = hg * 8 - 1 + r, gx = col - 1;
        float v = 0.f;
        if ((unsigned)gy < 64u && (unsigned)gx < 64u)
            v = flow8[((size_t)(n * 2 + c)) * HWSZ + gy * 64 + gx];
        s_fl[c][r][col] = v;
    }
    if (tid < 144) s_bias[tid >> 4][tid & 15] = mk_b2[(tid >> 4) * 256 + uvt * 16 + (tid & 15)];
    __syncthreads();

    const int h = hg * 8 + wv;
    f32x4 acc[9][4];
#pragma unroll
    for (int k = 0; k < 9; ++k)
#pragma unroll
        for (int q = 0; q < 4; ++q) acc[k][q] = (f32x4){0.f, 0.f, 0.f, 0.f};

    const unsigned short* mb = m_frag + (size_t)(n * 256 + h * 4) * 4096 + lg * 128 + ln * 8;
    const unsigned short* wk0 = s_w + lg * 128 + ln * 8;

    s16x8 bq[4], bnx[4];
#pragma unroll
    for (int q = 0; q < 4; ++q) bq[q] = *(const s16x8*)&mb[q * 4096];
#pragma unroll
    for (int ks = 0; ks < 8; ++ks) {
        if (ks < 7) {
#pragma unroll
            for (int q = 0; q < 4; ++q) bnx[q] = *(const s16x8*)&mb[q * 4096 + (ks + 1) * 512];
        }
        const unsigned short* wk = wk0 + ks * 512;
#pragma unroll
        for (int k = 0; k < 9; ++k) {
            s16x8 af = *(const s16x8*)&wk[k * 4096];
#pragma unroll
            for (int q = 0; q < 4; ++q)
                acc[k][q] = __builtin_amdgcn_mfma_f32_16x16x32_bf16(af, bq[q], acc[k][q], 0, 0, 0);
        }
#pragma unroll
        for (int q = 0; q < 4; ++q) bq[q] = bnx[q];
    }

    // epilogue: softmax over k + convex combine + coalesced float4 stores
#pragma unroll
    for (int q = 0; q < 4; ++q) {
        const int w = q * 16 + ln;
        float o0[4], o1[4];
#pragma unroll
        for (int r = 0; r < 4; ++r) {
            const int vv = lg * 4 + r;
            float p[9], mx = -1e30f;
#pragma unroll
            for (int k = 0; k < 9; ++k) {
                p[k] = (acc[k][q][r] + s_bias[k][vv]) * 0.25f;
                mx = fmaxf(mx, p[k]);
            }
            float sum = 0.f;
#pragma unroll
            for (int k = 0; k < 9; ++k) { p[k] = __expf(p[k] - mx); sum += p[k]; }
            float inv = 1.0f / sum;
            float a0 = 0.f, a1 = 0.f;
#pragma unroll
            for (int k = 0; k < 9; ++k) {
                const int dy = k / 3, dx = k % 3;
                a0 += p[k] * s_fl[0][wv + dy][w + dx];
                a1 += p[k] * s_fl[1][wv + dy][w + dx];
            }
            o0[r] = a0 * inv; o1[r] = a1 * inv;
        }
        float* base0 = out + ((size_t)(n * 2 + 0) * 1024 + h * 16 + uvt) * 1024 + w * 16 + lg * 4;
        float* base1 = out + ((size_t)(n * 2 + 1) * 1024 + h * 16 + uvt) * 1024 + w * 16 + lg * 4;
        *(f32x4*)base0 = (f32x4){o0[0], o0[1], o0[2], o0[3]};
        *(f32x4*)base1 = (f32x4){o1[0], o1[1], o1[2], o1[3]};
    }
}

// ---------------------------------------------------------------------------
extern "C" void kernel_launch(void* const* d_in, const int* in_sizes, int n_in,
                              void* d_out, int out_size, void* d_ws, size_t ws_size,
                              hipStream_t stream) {
    const float* img   = (const float*)d_in[0];
    const float* fh_w1 = (const float*)d_in[1];
    const float* fh_b1 = (const float*)d_in[2];
    const float* fh_g  = (const float*)d_in[3];
    const float* fh_be = (const float*)d_in[4];
    const float* fh_w2 = (const float*)d_in[5];
    const float* fh_b2 = (const float*)d_in[6];
    const float* mk_w1 = (const float*)d_in[7];
    const float* mk_b1 = (const float*)d_in[8];
    const float* mk_g  = (const float*)d_in[9];
    const float* mk_be = (const float*)d_in[10];
    const float* mk_w2 = (const float*)d_in[11];
    const float* mk_b2 = (const float*)d_in[12];
    float* out = (float*)d_out;

    char* p = (char*)d_ws;
    unsigned short* w2f    = (unsigned short*)p;  p += (size_t)1179648;
    unsigned short* w1f    = (unsigned short*)p;  p += (size_t)663552;
    unsigned short* imgT   = (unsigned short*)p;  p += (size_t)4194304;
    unsigned short* m_frag = (unsigned short*)p;  p += (size_t)8388608;
    float* h_pre  = (float*)p;  p += (size_t)131072;
    float* flow8  = (float*)p;  p += (size_t)131072;
    float* part   = (float*)p;  p += (size_t)131072;
    float* ab_m   = (float*)p;  p += 2048;
    float* ab_h   = (float*)p;  p += 64;

    prep_weights<<<2304, 256, 0, stream>>>(mk_w1, fh_w1, mk_w2, w1f, w2f);
    img_transpose<<<dim3(64, 4), 256, 0, stream>>>(img, imgT);
    conv1_mfma<<<dim3(64, 4), 512, 0, stream>>>(imgT, w1f, mk_b1, fh_b1, m_frag, h_pre);
    bn_stats<<<2, 256, 0, stream>>>(h_pre, fh_g, fh_be, ab_h, 2);
    bn_partial<<<64, 256, 0, stream>>>(m_frag, part);
    bn_final<<<1, 256, 0, stream>>>(part, mk_g, mk_be, ab_m);
    flow_conv2<<<128, 256, 0, stream>>>(h_pre, ab_h, fh_w2, fh_b2, flow8);
    bnrelu_frag<<<2048, 256, 0, stream>>>(m_frag, ab_m);
    mask_combine_mfma<<<dim3(8, 16, 4), 512, 0, stream>>>(m_frag, w2f, mk_b2, flow8, out);
}

// Round 4
// 111.840 us; speedup vs baseline: 5.8886x; 1.0992x over previous
//
#include <hip/hip_runtime.h>
#include <hip/hip_bf16.h>

#define N_B   4
#define C_IN  128
#define HWSZ  4096
#define C_M   256

typedef __attribute__((ext_vector_type(8))) short          s16x8;   // bf16x8 frag (4 VGPR)
typedef __attribute__((ext_vector_type(8))) unsigned short u16x8;
typedef __attribute__((ext_vector_type(4))) unsigned short u16x4;
typedef __attribute__((ext_vector_type(4))) float          f32x4;

__device__ __forceinline__ unsigned short f2bf(float f) {
    union { float f; unsigned u; } v; v.f = f;
    unsigned r = v.u + 0x7fffu + ((v.u >> 16) & 1u);   // RNE
    return (unsigned short)(r >> 16);
}
__device__ __forceinline__ float bf2f(unsigned short u) {
    union { unsigned u; float f; } v; v.u = ((unsigned)u) << 16; return v.f;
}

// ---------------------------------------------------------------------------
// K1: fused prep. Blocks 0..255: img transpose (n,ci,h,w)->bf16 (n,h,w,ci).
// Blocks 256..2559: fragment-ordered weights.
//  w1f[z2][cc4][tap9][g9][lane64][j8]; row=g*16+(lane&15), ci=cc*32+(lane>>4)*8+j
//  w2f[uvt16][k9][ks8][lg4][ln16][j8] = 0.25*mk_w2[(k*256+uvt*16+ln)*256+ks*32+lg*8+j]
// ---------------------------------------------------------------------------
__global__ void __launch_bounds__(256)
prep_all(const float* __restrict__ img,
         const float* __restrict__ mk_w1, const float* __restrict__ fh_w1,
         const float* __restrict__ mk_w2,
         unsigned short* __restrict__ imgT,
         unsigned short* __restrict__ w1f, unsigned short* __restrict__ w2f)
{
    __shared__ float s[128][65];
    const int b = blockIdx.x;
    if (b < 256) {
        const int n = b >> 6, h = b & 63;
        const float* src = img + (size_t)n * C_IN * HWSZ + h * 64;
        for (int i = threadIdx.x; i < 128 * 64; i += 256) {
            int ci = i >> 6, w = i & 63;
            s[ci][w] = src[(size_t)ci * HWSZ + w];
        }
        __syncthreads();
        unsigned short* dst = imgT + ((size_t)(n * 64 + h) * 64) * 128;
        for (int i = threadIdx.x; i < 64 * 128; i += 256) {
            int w = i >> 7, ci = i & 127;
            dst[(size_t)w * 128 + ci] = f2bf(s[ci][w]);
        }
        return;
    }
    int i = (b - 256) * 256 + threadIdx.x;
    if (i < 2304 * 256) {
        int uvt = i / 36864;
        int r   = i - uvt * 36864;
        int k   = r / 4096;
        int r2  = r - k * 4096;
        int ks  = r2 >> 9;
        int lg  = (r2 >> 7) & 3;
        int ln  = (r2 >> 3) & 15;
        int j   = r2 & 7;
        w2f[i] = f2bf(0.25f * mk_w2[(size_t)(k * 256 + uvt * 16 + ln) * 256 + ks * 32 + lg * 8 + j]);
    }
    if (i < 2 * 4 * 9 * 9 * 512) {
        int z   = i / 165888;
        int r   = i - z * 165888;
        int cc  = r / 41472;
        int r2  = r - cc * 41472;
        int tap = r2 / 4608;
        int r3  = r2 - tap * 4608;
        int g   = r3 / 512;
        int r4  = r3 - g * 512;
        int lane = r4 >> 3, j = r4 & 7;
        int lg = lane >> 4, ln = lane & 15;
        int row = g * 16 + ln;
        int ci  = cc * 32 + lg * 8 + j;
        float w = 0.f;
        if (z == 0) {
            if (row < 128)      w = mk_w1[((size_t)row * C_IN + ci) * 9 + tap];
            else if (row < 130) w = fh_w1[((size_t)(row - 128) * C_IN + ci) * 9 + tap];
        } else {
            if (row < 128)      w = mk_w1[((size_t)(128 + row) * C_IN + ci) * 9 + tap];
        }
        w1f[i] = f2bf(w);
    }
}

// ---------------------------------------------------------------------------
// K2: conv1 implicit-GEMM 3x3, one block per image row (64,4), 512 thr.
// 8 waves = (z2, gq4); wave covers full 64-px row (q=4), g-tile subset.
// af streamed from L2 (fragment-ordered), reused over 4 q -> 1 load : 4 MFMA.
// Writes m_frag (bf16, biased, pre-BN) + h_pre (fp32 flow head).
// ---------------------------------------------------------------------------
__global__ void __launch_bounds__(512)
conv1_mfma(const unsigned short* __restrict__ imgT,
           const unsigned short* __restrict__ w1f,
           const float* __restrict__ mk_b1, const float* __restrict__ fh_b1,
           unsigned short* __restrict__ m_frag, float* __restrict__ h_pre)
{
    __shared__ unsigned short s_img[3][66][40];   // 15,840 B
    __shared__ float s_bias[2][144];

    const int h = blockIdx.x;
    const int n = blockIdx.y;
    const int tid = threadIdx.x;
    const int wv = tid >> 6, lane = tid & 63;
    const int lg = lane >> 4, ln = lane & 15;
    const int z = wv >> 2, gq = wv & 3;
    const int g0 = z ? (gq * 2) : ((int[4]){0, 3, 5, 7})[gq];
    const int gn = z ? 2 : ((int[4]){3, 2, 2, 2})[gq];

    if (tid < 288) {
        int zz = tid / 144, cl = tid - zz * 144;
        float b = 0.f;
        if (zz == 0) {
            if (cl < 128)      b = mk_b1[cl];
            else if (cl < 130) b = fh_b1[cl - 128];
        } else if (cl < 128)   b = mk_b1[128 + cl];
        s_bias[zz][cl] = b;
    }

    f32x4 acc[3][4];
#pragma unroll
    for (int g = 0; g < 3; ++g)
#pragma unroll
        for (int q = 0; q < 4; ++q) acc[g][q] = (f32x4){0.f, 0.f, 0.f, 0.f};

    for (int cc = 0; cc < 4; ++cc) {
        __syncthreads();
        for (int i = tid; i < 3 * 66 * 4; i += 512) {
            int r = i / 264;
            int rem = i - r * 264;
            int c = rem >> 2, un = rem & 3;
            int gy = h - 1 + r, gx = c - 1;
            u16x8 v = {0, 0, 0, 0, 0, 0, 0, 0};
            if ((unsigned)gy < 64u && (unsigned)gx < 64u)
                v = *(const u16x8*)&imgT[((size_t)((n * 64 + gy) * 64 + gx)) * 128 + cc * 32 + un * 8];
            *(u16x8*)&s_img[r][c][un * 8] = v;
        }
        __syncthreads();

        const unsigned short* wfp = w1f + (size_t)(z * 4 + cc) * 81 * 512 + lane * 8;
#pragma unroll
        for (int tap = 0; tap < 9; ++tap) {
            const int dy = tap / 3, dx = tap % 3;
            s16x8 bf[4];
#pragma unroll
            for (int q = 0; q < 4; ++q)
                bf[q] = *(const s16x8*)&s_img[dy][q * 16 + ln + dx][lg * 8];
#pragma unroll
            for (int gi = 0; gi < 3; ++gi) {
                if (gi < gn) {
                    s16x8 af = *(const s16x8*)&wfp[(size_t)(tap * 9 + g0 + gi) * 512];
#pragma unroll
                    for (int q = 0; q < 4; ++q)
                        acc[gi][q] = __builtin_amdgcn_mfma_f32_16x16x32_bf16(af, bf[q], acc[gi][q], 0, 0, 0);
                }
            }
        }
    }

#pragma unroll
    for (int gi = 0; gi < 3; ++gi) {
        if (gi >= gn) continue;
        const int g = g0 + gi;
#pragma unroll
        for (int q = 0; q < 4; ++q) {
            const int px  = q * 16 + ln;
            const int pxg = h * 4 + q;
            if (z == 0 && g == 8) {
                if (lg == 0) {
#pragma unroll
                    for (int r = 0; r < 2; ++r)
                        h_pre[((size_t)(n * 2 + r)) * HWSZ + h * 64 + px] =
                            acc[gi][q][r] + s_bias[0][128 + r];
                }
            } else {
                u16x4 vv;
#pragma unroll
                for (int r = 0; r < 4; ++r)
                    vv[r] = f2bf(acc[gi][q][r] + s_bias[z][g * 16 + lg * 4 + r]);
                int ks  = z * 4 + (g >> 1);
                int lgp = ((g & 1) * 2 + (lg >> 1)) & 3;
                size_t off = ((((size_t)(n * 256 + pxg) * 8 + ks) * 4 + lgp) * 128) + ln * 8 + (lg & 1) * 4;
                *(u16x4*)&m_frag[off] = vv;
            }
        }
    }
}

// ---------------------------------------------------------------------------
// K3: BN partial sums over m_frag (blocks 0..63) + flow-head full BN stats
// (blocks 64,65 -> ab_h).
// ---------------------------------------------------------------------------
__global__ void __launch_bounds__(256)
bn_partial_flow(const unsigned short* __restrict__ m_frag,
                const float* __restrict__ h_pre,
                const float* __restrict__ fh_g, const float* __restrict__ fh_be,
                float* __restrict__ partial, float* __restrict__ ab_h)
{
    __shared__ float red[256][16];
    const int t = threadIdx.x, b = blockIdx.x;
    if (b >= 64) {
        const int c = b - 64;
        float s = 0.f, s2 = 0.f;
        for (int n = 0; n < N_B; ++n) {
            const float* p = h_pre + (size_t)(n * 2 + c) * HWSZ;
            for (int i = t; i < HWSZ; i += 256) {
                float v = p[i]; s += v; s2 += v * v;
            }
        }
#pragma unroll
        for (int off = 32; off > 0; off >>= 1) {
            s += __shfl_down(s, off, 64); s2 += __shfl_down(s2, off, 64);
        }
        const int wid = t >> 6, lane = t & 63;
        if (lane == 0) { red[wid][0] = s; red[wid][1] = s2; }
        __syncthreads();
        if (t == 0) {
            float S = red[0][0] + red[1][0] + red[2][0] + red[3][0];
            float S2 = red[0][1] + red[1][1] + red[2][1] + red[3][1];
            const float inv = 1.0f / (float)(N_B * HWSZ);
            float mu = S * inv;
            float var = S2 * inv - mu * mu;
            float r = rsqrtf(var + 1e-5f);
            float a = fh_g[c] * r;
            ab_h[2 * c] = a; ab_h[2 * c + 1] = fh_be[c] - mu * a;
        }
        return;
    }
    const int cu = t & 31, ks = cu >> 2, lg = cu & 3;
    float s[8], s2[8];
#pragma unroll
    for (int j = 0; j < 8; ++j) { s[j] = 0.f; s2[j] = 0.f; }
    for (int i = 0; i < 32; ++i) {
        int m = b * 256 + (t >> 5) * 32 + i;
        int ln = m & 15, pxg = (m >> 4) & 255, n = m >> 12;
        size_t off = ((((size_t)(n * 256 + pxg) * 8 + ks) * 4 + lg) * 16 + ln) * 8;
        u16x8 v = *(const u16x8*)&m_frag[off];
#pragma unroll
        for (int j = 0; j < 8; ++j) {
            float f = bf2f(v[j]); s[j] += f; s2[j] += f * f;
        }
    }
#pragma unroll
    for (int j = 0; j < 8; ++j) { red[t][j] = s[j]; red[t][8 + j] = s2[j]; }
    __syncthreads();
    {
        int c = t, cuu = c >> 3, j = c & 7;
        float S = 0.f, S2 = 0.f;
#pragma unroll
        for (int w = 0; w < 8; ++w) { S += red[cuu + w * 32][j]; S2 += red[cuu + w * 32][8 + j]; }
        partial[(size_t)(b * 256 + c) * 2] = S;
        partial[(size_t)(b * 256 + c) * 2 + 1] = S2;
    }
}

__global__ void __launch_bounds__(256)
bn_final(const float* __restrict__ partial, const float* __restrict__ gamma,
         const float* __restrict__ beta, float* __restrict__ ab)
{
    int c = threadIdx.x;
    float S = 0.f, S2 = 0.f;
    for (int b = 0; b < 64; ++b) {
        S += partial[(size_t)(b * 256 + c) * 2];
        S2 += partial[(size_t)(b * 256 + c) * 2 + 1];
    }
    const float inv = 1.0f / (float)(N_B * HWSZ);
    float mu = S * inv;
    float var = S2 * inv - mu * mu;
    float r = rsqrtf(var + 1e-5f);
    float a = gamma[c] * r;
    ab[2 * c] = a; ab[2 * c + 1] = beta[c] - mu * a;
}

// ---------------------------------------------------------------------------
// K5: blocks 0..2047 in-place BN+ReLU on m_frag; blocks 2048..2175 flow conv2.
// ---------------------------------------------------------------------------
__global__ void __launch_bounds__(256)
bnrelu_flow(unsigned short* __restrict__ m_frag, const float* __restrict__ ab,
            const float* __restrict__ hpre, const float* __restrict__ ab_h,
            const float* __restrict__ w2, const float* __restrict__ b2,
            float* __restrict__ flow8)
{
    __shared__ float s_ab[512];
    const int t = threadIdx.x;
    if (blockIdx.x < 2048) {
        s_ab[t] = ab[t]; s_ab[256 + t] = ab[256 + t];
        __syncthreads();
        const unsigned u = blockIdx.x * 256 + t;
        const int lg = (u >> 4) & 3, ks = (u >> 7) & 7;
        const int cb = ks * 32 + lg * 8;
        u16x8 v = *(const u16x8*)&m_frag[(size_t)u * 8];
        u16x8 o;
#pragma unroll
        for (int j = 0; j < 8; ++j) {
            float a = s_ab[2 * (cb + j)], b = s_ab[2 * (cb + j) + 1];
            o[j] = f2bf(fmaxf(a * bf2f(v[j]) + b, 0.f));
        }
        *(u16x8*)&m_frag[(size_t)u * 8] = o;
        return;
    }
    int idx = (blockIdx.x - 2048) * 256 + t;
    int w = idx & 63, h = (idx >> 6) & 63, co = (idx >> 12) & 1, n = idx >> 13;
    float acc = b2[co];
#pragma unroll
    for (int ci = 0; ci < 2; ++ci) {
        float a = ab_h[2 * ci], b = ab_h[2 * ci + 1];
        const float* p = hpre + (size_t)(n * 2 + ci) * HWSZ;
        const float* wp = &w2[(co * 2 + ci) * 9];
#pragma unroll
        for (int dy = 0; dy < 3; ++dy)
#pragma unroll
            for (int dx = 0; dx < 3; ++dx) {
                int gy = h + dy - 1, gx = w + dx - 1;
                float v = 0.f;
                if ((unsigned)gy < 64u && (unsigned)gx < 64u)
                    v = fmaxf(a * p[gy * 64 + gx] + b, 0.f);
                acc += wp[dy * 3 + dx] * v;
            }
    }
    flow8[idx] = acc * 8.0f;
}

// ---------------------------------------------------------------------------
// K6: fused 1x1-conv GEMM + bias + softmax(9) + convex upsample.
// grid (4,16,4) = 256 blocks, 512 thr (8 waves, one row each), 2 row-passes
// per block reusing the staged W tile. 0.25 pre-folded into W/bias.
// ---------------------------------------------------------------------------
__global__ void __launch_bounds__(512)
mask_combine_mfma(const unsigned short* __restrict__ m_frag,
                  const unsigned short* __restrict__ w2f,
                  const float* __restrict__ mk_b2,
                  const float* __restrict__ flow8,
                  float* __restrict__ out)
{
    __shared__ unsigned short s_w[36864];       // 73,728 B fragment order
    __shared__ float s_fl[2][18][66];           // 9,504 B
    __shared__ float s_bias[9][16];

    const int hg = blockIdx.x, uvt = blockIdx.y, n = blockIdx.z;
    const int tid = threadIdx.x;
    const int wv = tid >> 6, lane = tid & 63;
    const int lg = lane >> 4, ln = lane & 15;

    {
        const u16x8* wsrc = (const u16x8*)(w2f + (size_t)uvt * 36864);
        u16x8* wdst = (u16x8*)s_w;
        for (int i = tid; i < 4608; i += 512) wdst[i] = wsrc[i];
    }
    for (int i = tid; i < 2 * 18 * 66; i += 512) {
        int c = i / 1188, rem = i - c * 1188, r = rem / 66, col = rem - r * 66;
        int gy = hg * 16 - 1 + r, gx = col - 1;
        float v = 0.f;
        if ((unsigned)gy < 64u && (unsigned)gx < 64u)
            v = flow8[((size_t)(n * 2 + c)) * HWSZ + gy * 64 + gx];
        s_fl[c][r][col] = v;
    }
    if (tid < 144) s_bias[tid >> 4][tid & 15] = 0.25f * mk_b2[(tid >> 4) * 256 + uvt * 16 + (tid & 15)];
    __syncthreads();

    const unsigned short* wk0 = s_w + lg * 128 + ln * 8;
    const int h0 = hg * 16 + wv;
    const unsigned short* mb0 = m_frag + (size_t)(n * 256 + h0 * 4) * 4096 + lg * 128 + ln * 8;
    const unsigned short* mb1 = mb0 + (size_t)8 * 4 * 4096;

    f32x4 acc[9][4];
    s16x8 bq[4], bnx[4], bq1[4];

    // ---- pass 0 ----
#pragma unroll
    for (int k = 0; k < 9; ++k)
#pragma unroll
        for (int q = 0; q < 4; ++q) acc[k][q] = (f32x4){0.f, 0.f, 0.f, 0.f};
#pragma unroll
    for (int q = 0; q < 4; ++q) bq[q] = *(const s16x8*)&mb0[q * 4096];
#pragma unroll
    for (int ks = 0; ks < 8; ++ks) {
        if (ks < 7) {
#pragma unroll
            for (int q = 0; q < 4; ++q) bnx[q] = *(const s16x8*)&mb0[q * 4096 + (ks + 1) * 512];
        }
        const unsigned short* wk = wk0 + ks * 512;
#pragma unroll
        for (int k = 0; k < 9; ++k) {
            s16x8 af = *(const s16x8*)&wk[k * 4096];
#pragma unroll
            for (int q = 0; q < 4; ++q)
                acc[k][q] = __builtin_amdgcn_mfma_f32_16x16x32_bf16(af, bq[q], acc[k][q], 0, 0, 0);
        }
#pragma unroll
        for (int q = 0; q < 4; ++q) bq[q] = bnx[q];
    }
    // prefetch pass-1 B fragments so L2 latency hides under the epilogue VALU
#pragma unroll
    for (int q = 0; q < 4; ++q) bq1[q] = *(const s16x8*)&mb1[q * 4096];

#pragma unroll
    for (int q = 0; q < 4; ++q) {
        const int w = q * 16 + ln;
        float o0[4], o1[4];
#pragma unroll
        for (int r = 0; r < 4; ++r) {
            const int vv = lg * 4 + r;
            float p[9], mx = -1e30f;
#pragma unroll
            for (int k = 0; k < 9; ++k) {
                p[k] = acc[k][q][r] + s_bias[k][vv];
                mx = fmaxf(mx, p[k]);
            }
            float sum = 0.f;
#pragma unroll
            for (int k = 0; k < 9; ++k) { p[k] = __expf(p[k] - mx); sum += p[k]; }
            float inv = 1.0f / sum;
            float a0 = 0.f, a1 = 0.f;
#pragma unroll
            for (int k = 0; k < 9; ++k) {
                const int dy = k / 3, dx = k % 3;
                a0 += p[k] * s_fl[0][wv + dy][w + dx];
                a1 += p[k] * s_fl[1][wv + dy][w + dx];
            }
            o0[r] = a0 * inv; o1[r] = a1 * inv;
        }
        float* base0 = out + ((size_t)(n * 2 + 0) * 1024 + h0 * 16 + uvt) * 1024 + w * 16 + lg * 4;
        float* base1 = out + ((size_t)(n * 2 + 1) * 1024 + h0 * 16 + uvt) * 1024 + w * 16 + lg * 4;
        *(f32x4*)base0 = (f32x4){o0[0], o0[1], o0[2], o0[3]};
        *(f32x4*)base1 = (f32x4){o1[0], o1[1], o1[2], o1[3]};
    }

    // ---- pass 1 ----
    const int h1 = h0 + 8;
#pragma unroll
    for (int k = 0; k < 9; ++k)
#pragma unroll
        for (int q = 0; q < 4; ++q) acc[k][q] = (f32x4){0.f, 0.f, 0.f, 0.f};
#pragma unroll
    for (int ks = 0; ks < 8; ++ks) {
        if (ks < 7) {
#pragma unroll
            for (int q = 0; q < 4; ++q) bnx[q] = *(const s16x8*)&mb1[q * 4096 + (ks + 1) * 512];
        }
        const unsigned short* wk = wk0 + ks * 512;
#pragma unroll
        for (int k = 0; k < 9; ++k) {
            s16x8 af = *(const s16x8*)&wk[k * 4096];
#pragma unroll
            for (int q = 0; q < 4; ++q)
                acc[k][q] = __builtin_amdgcn_mfma_f32_16x16x32_bf16(af, bq1[q], acc[k][q], 0, 0, 0);
        }
#pragma unroll
        for (int q = 0; q < 4; ++q) bq1[q] = bnx[q];
    }
#pragma unroll
    for (int q = 0; q < 4; ++q) {
        const int w = q * 16 + ln;
        float o0[4], o1[4];
#pragma unroll
        for (int r = 0; r < 4; ++r) {
            const int vv = lg * 4 + r;
            float p[9], mx = -1e30f;
#pragma unroll
            for (int k = 0; k < 9; ++k) {
                p[k] = acc[k][q][r] + s_bias[k][vv];
                mx = fmaxf(mx, p[k]);
            }
            float sum = 0.f;
#pragma unroll
            for (int k = 0; k < 9; ++k) { p[k] = __expf(p[k] - mx); sum += p[k]; }
            float inv = 1.0f / sum;
            float a0 = 0.f, a1 = 0.f;
#pragma unroll
            for (int k = 0; k < 9; ++k) {
                const int dy = k / 3, dx = k % 3;
                a0 += p[k] * s_fl[0][8 + wv + dy][w + dx];
                a1 += p[k] * s_fl[1][8 + wv + dy][w + dx];
            }
            o0[r] = a0 * inv; o1[r] = a1 * inv;
        }
        float* base0 = out + ((size_t)(n * 2 + 0) * 1024 + h1 * 16 + uvt) * 1024 + w * 16 + lg * 4;
        float* base1 = out + ((size_t)(n * 2 + 1) * 1024 + h1 * 16 + uvt) * 1024 + w * 16 + lg * 4;
        *(f32x4*)base0 = (f32x4){o0[0], o0[1], o0[2], o0[3]};
        *(f32x4*)base1 = (f32x4){o1[0], o1[1], o1[2], o1[3]};
    }
}

// ---------------------------------------------------------------------------
extern "C" void kernel_launch(void* const* d_in, const int* in_sizes, int n_in,
                              void* d_out, int out_size, void* d_ws, size_t ws_size,
                              hipStream_t stream) {
    const float* img   = (const float*)d_in[0];
    const float* fh_w1 = (const float*)d_in[1];
    const float* fh_b1 = (const float*)d_in[2];
    const float* fh_g  = (const float*)d_in[3];
    const float* fh_be = (const float*)d_in[4];
    const float* fh_w2 = (const float*)d_in[5];
    const float* fh_b2 = (const float*)d_in[6];
    const float* mk_w1 = (const float*)d_in[7];
    const float* mk_b1 = (const float*)d_in[8];
    const float* mk_g  = (const float*)d_in[9];
    const float* mk_be = (const float*)d_in[10];
    const float* mk_w2 = (const float*)d_in[11];
    const float* mk_b2 = (const float*)d_in[12];
    float* out = (float*)d_out;

    char* p = (char*)d_ws;
    unsigned short* w2f    = (unsigned short*)p;  p += (size_t)1179648;
    unsigned short* w1f    = (unsigned short*)p;  p += (size_t)663552;
    unsigned short* imgT   = (unsigned short*)p;  p += (size_t)4194304;
    unsigned short* m_frag = (unsigned short*)p;  p += (size_t)8388608;
    float* h_pre  = (float*)p;  p += (size_t)131072;
    float* flow8  = (float*)p;  p += (size_t)131072;
    float* part   = (float*)p;  p += (size_t)131072;
    float* ab_m   = (float*)p;  p += 2048;
    float* ab_h   = (float*)p;  p += 64;

    prep_all<<<2560, 256, 0, stream>>>(img, mk_w1, fh_w1, mk_w2, imgT, w1f, w2f);
    conv1_mfma<<<dim3(64, 4), 512, 0, stream>>>(imgT, w1f, mk_b1, fh_b1, m_frag, h_pre);
    bn_partial_flow<<<66, 256, 0, stream>>>(m_frag, h_pre, fh_g, fh_be, part, ab_h);
    bn_final<<<1, 256, 0, stream>>>(part, mk_g, mk_be, ab_m);
    bnrelu_flow<<<2176, 256, 0, stream>>>(m_frag, ab_m, h_pre, ab_h, fh_w2, fh_b2, flow8);
    mask_combine_mfma<<<dim3(4, 16, 4), 512, 0, stream>>>(m_frag, w2f, mk_b2, flow8, out);
}

// Round 5
// 107.735 us; speedup vs baseline: 6.1130x; 1.0381x over previous
//
#include <hip/hip_runtime.h>
#include <hip/hip_bf16.h>

#define N_B   4
#define C_IN  128
#define HWSZ  4096
#define C_M   256

typedef __attribute__((ext_vector_type(8))) short          s16x8;   // bf16x8 frag (4 VGPR)
typedef __attribute__((ext_vector_type(8))) unsigned short u16x8;
typedef __attribute__((ext_vector_type(4))) unsigned short u16x4;
typedef __attribute__((ext_vector_type(4))) float          f32x4;

__device__ __forceinline__ unsigned short f2bf(float f) {
    union { float f; unsigned u; } v; v.f = f;
    unsigned r = v.u + 0x7fffu + ((v.u >> 16) & 1u);   // RNE
    return (unsigned short)(r >> 16);
}
__device__ __forceinline__ float bf2f(unsigned short u) {
    union { unsigned u; float f; } v; v.u = ((unsigned)u) << 16; return v.f;
}

// ---------------------------------------------------------------------------
// K1: fused prep. Blocks 0..255: img transpose (n,ci,h,w)->bf16 (n,h,w,ci).
// Blocks 256..2559: fragment-ordered weights.
//  w1f[z2][cc4][tap9][g9][lane64][j8]; row=g*16+(lane&15), ci=cc*32+(lane>>4)*8+j
//  w2f[uvt16][k9][ks8][lg4][ln16][j8] = 0.25*mk_w2[(k*256+uvt*16+ln)*256+ks*32+lg*8+j]
// ---------------------------------------------------------------------------
__global__ void __launch_bounds__(256)
prep_all(const float* __restrict__ img,
         const float* __restrict__ mk_w1, const float* __restrict__ fh_w1,
         const float* __restrict__ mk_w2,
         unsigned short* __restrict__ imgT,
         unsigned short* __restrict__ w1f, unsigned short* __restrict__ w2f)
{
    __shared__ float s[128][65];
    const int b = blockIdx.x;
    if (b < 256) {
        const int n = b >> 6, h = b & 63;
        const float* src = img + (size_t)n * C_IN * HWSZ + h * 64;
        for (int i = threadIdx.x; i < 128 * 64; i += 256) {
            int ci = i >> 6, w = i & 63;
            s[ci][w] = src[(size_t)ci * HWSZ + w];
        }
        __syncthreads();
        unsigned short* dst = imgT + ((size_t)(n * 64 + h) * 64) * 128;
        for (int i = threadIdx.x; i < 64 * 128; i += 256) {
            int w = i >> 7, ci = i & 127;
            dst[(size_t)w * 128 + ci] = f2bf(s[ci][w]);
        }
        return;
    }
    int i = (b - 256) * 256 + threadIdx.x;
    if (i < 2304 * 256) {
        int uvt = i / 36864;
        int r   = i - uvt * 36864;
        int k   = r / 4096;
        int r2  = r - k * 4096;
        int ks  = r2 >> 9;
        int lg  = (r2 >> 7) & 3;
        int ln  = (r2 >> 3) & 15;
        int j   = r2 & 7;
        w2f[i] = f2bf(0.25f * mk_w2[(size_t)(k * 256 + uvt * 16 + ln) * 256 + ks * 32 + lg * 8 + j]);
    }
    if (i < 2 * 4 * 9 * 9 * 512) {
        int z   = i / 165888;
        int r   = i - z * 165888;
        int cc  = r / 41472;
        int r2  = r - cc * 41472;
        int tap = r2 / 4608;
        int r3  = r2 - tap * 4608;
        int g   = r3 / 512;
        int r4  = r3 - g * 512;
        int lane = r4 >> 3, j = r4 & 7;
        int lg = lane >> 4, ln = lane & 15;
        int row = g * 16 + ln;
        int ci  = cc * 32 + lg * 8 + j;
        float w = 0.f;
        if (z == 0) {
            if (row < 128)      w = mk_w1[((size_t)row * C_IN + ci) * 9 + tap];
            else if (row < 130) w = fh_w1[((size_t)(row - 128) * C_IN + ci) * 9 + tap];
        } else {
            if (row < 128)      w = mk_w1[((size_t)(128 + row) * C_IN + ci) * 9 + tap];
        }
        w1f[i] = f2bf(w);
    }
}

// ---------------------------------------------------------------------------
// K2: conv1 implicit-GEMM 3x3. Grid 512 (XCD-swizzled (n,h,z)), 512 thr,
// 2 blocks/CU -> 4 waves/SIMD. Wave = (gq4, half2): q=2 px-groups, 2-3 g.
// Also computes per-block BN channel partials (fp32, deterministic).
// m_frag unit: [n][pxg256][ks8][lg4][ln16][j8], c = ks*32+lg*8+j.
// ---------------------------------------------------------------------------
__global__ void __launch_bounds__(512, 4)
conv1_mfma(const unsigned short* __restrict__ imgT,
           const unsigned short* __restrict__ w1f,
           const float* __restrict__ mk_b1, const float* __restrict__ fh_b1,
           unsigned short* __restrict__ m_frag, float* __restrict__ h_pre,
           float* __restrict__ ps_s, float* __restrict__ ps_s2)
{
    __shared__ unsigned short s_img[3][66][40];   // 15,840 B
    __shared__ float s_bias[144];
    __shared__ float s_ps[2][144], s_ps2[2][144];

    const int hw = blockIdx.x;
    const int xcd = hw & 7, slot = hw >> 3;
    const int lid = xcd * 64 + slot;
    const int n = lid >> 7, h = (lid >> 1) & 63, z = lid & 1;
    const int hn = n * 64 + h;

    const int tid = threadIdx.x;
    const int wv = tid >> 6, lane = tid & 63;
    const int lg = lane >> 4, ln = lane & 15;
    const int gq = wv >> 1, half = wv & 1;
    const int g0 = z ? (gq * 2) : ((int[4]){0, 3, 5, 7})[gq];
    const int gn = z ? 2 : ((int[4]){3, 2, 2, 2})[gq];

    if (tid < 144) {
        float b = 0.f;
        if (z == 0) {
            if (tid < 128)      b = mk_b1[tid];
            else if (tid < 130) b = fh_b1[tid - 128];
        } else if (tid < 128)   b = mk_b1[128 + tid];
        s_bias[tid] = b;
    }

    f32x4 acc[3][2];
#pragma unroll
    for (int g = 0; g < 3; ++g)
#pragma unroll
        for (int q = 0; q < 2; ++q) acc[g][q] = (f32x4){0.f, 0.f, 0.f, 0.f};

    for (int cc = 0; cc < 4; ++cc) {
        __syncthreads();
        for (int i = tid; i < 3 * 66 * 4; i += 512) {
            int r = i / 264;
            int rem = i - r * 264;
            int c = rem >> 2, un = rem & 3;
            int gy = h - 1 + r, gx = c - 1;
            u16x8 v = {0, 0, 0, 0, 0, 0, 0, 0};
            if ((unsigned)gy < 64u && (unsigned)gx < 64u)
                v = *(const u16x8*)&imgT[((size_t)((n * 64 + gy) * 64 + gx)) * 128 + cc * 32 + un * 8];
            *(u16x8*)&s_img[r][c][un * 8] = v;
        }
        __syncthreads();

        const unsigned short* wfp = w1f + (size_t)(z * 4 + cc) * 81 * 512 + lane * 8;
#pragma unroll
        for (int tap = 0; tap < 9; ++tap) {
            const int dy = tap / 3, dx = tap % 3;
            s16x8 bf[2];
#pragma unroll
            for (int q = 0; q < 2; ++q)
                bf[q] = *(const s16x8*)&s_img[dy][half * 32 + q * 16 + ln + dx][lg * 8];
#pragma unroll
            for (int gi = 0; gi < 3; ++gi) {
                if (gi < gn) {
                    s16x8 af = *(const s16x8*)&wfp[(size_t)(tap * 9 + g0 + gi) * 512];
#pragma unroll
                    for (int q = 0; q < 2; ++q)
                        acc[gi][q] = __builtin_amdgcn_mfma_f32_16x16x32_bf16(af, bf[q], acc[gi][q], 0, 0, 0);
                }
            }
        }
    }

    // epilogue: stores + per-channel partial stats
#pragma unroll
    for (int gi = 0; gi < 3; ++gi) {
        if (gi >= gn) continue;
        const int g = g0 + gi;
        float v[2][4];
#pragma unroll
        for (int q = 0; q < 2; ++q)
#pragma unroll
            for (int r = 0; r < 4; ++r)
                v[q][r] = acc[gi][q][r] + s_bias[g * 16 + lg * 4 + r];
        // stores
#pragma unroll
        for (int q = 0; q < 2; ++q) {
            const int px  = half * 32 + q * 16 + ln;
            const int pxg = h * 4 + half * 2 + q;
            if (z == 0 && g == 8) {
                if (lg == 0) {
#pragma unroll
                    for (int r = 0; r < 2; ++r)
                        h_pre[((size_t)(n * 2 + r)) * HWSZ + h * 64 + px] = v[q][r];
                }
            } else {
                u16x4 vv;
#pragma unroll
                for (int r = 0; r < 4; ++r) vv[r] = f2bf(v[q][r]);
                int ks  = z * 4 + (g >> 1);
                int lgp = ((g & 1) * 2 + (lg >> 1)) & 3;
                size_t off = ((((size_t)(n * 256 + pxg) * 8 + ks) * 4 + lgp) * 128) + ln * 8 + (lg & 1) * 4;
                *(u16x4*)&m_frag[off] = vv;
            }
        }
        // partial stats (sum over this wave's 32 px, then over 16 ln lanes)
#pragma unroll
        for (int r = 0; r < 4; ++r) {
            float s  = v[0][r] + v[1][r];
            float s2 = v[0][r] * v[0][r] + v[1][r] * v[1][r];
#pragma unroll
            for (int off = 1; off < 16; off <<= 1) {
                s  += __shfl_xor(s,  off, 64);
                s2 += __shfl_xor(s2, off, 64);
            }
            if (ln == 0) {
                s_ps[half][g * 16 + lg * 4 + r]  = s;
                s_ps2[half][g * 16 + lg * 4 + r] = s2;
            }
        }
    }
    __syncthreads();
    const int nch = z ? 128 : 130;
    if (tid < nch) {
        const int idx = z * 146 + tid;
        ps_s[(size_t)idx * 256 + hn]  = s_ps[0][tid] + s_ps[1][tid];
        ps_s2[(size_t)idx * 256 + hn] = s_ps2[0][tid] + s_ps2[1][tid];
    }
}

// ---------------------------------------------------------------------------
// K3: final BN stat reduction -> affine (a,b) for mask head (256 ch) and
// flow head (2 ch). One block, 288 active threads.
// ---------------------------------------------------------------------------
__global__ void __launch_bounds__(320)
bn_final2(const float* __restrict__ ps_s, const float* __restrict__ ps_s2,
          const float* __restrict__ mk_g, const float* __restrict__ mk_be,
          const float* __restrict__ fh_g, const float* __restrict__ fh_be,
          float* __restrict__ ab_m, float* __restrict__ ab_h)
{
    const int t = threadIdx.x;
    if (t >= 258) return;
    int idx;
    if (t < 256) idx = (t >> 7) * 146 + (t & 127);
    else         idx = 128 + (t - 256);
    float S = 0.f, S2 = 0.f;
    const float* p1 = ps_s  + (size_t)idx * 256;
    const float* p2 = ps_s2 + (size_t)idx * 256;
    for (int i = 0; i < 256; ++i) { S += p1[i]; S2 += p2[i]; }
    const float inv = 1.0f / (float)(N_B * HWSZ);
    float mu = S * inv;
    float var = S2 * inv - mu * mu;
    float r = rsqrtf(var + 1e-5f);
    if (t < 256) {
        float a = mk_g[t] * r;
        ab_m[2 * t] = a; ab_m[2 * t + 1] = mk_be[t] - mu * a;
    } else {
        int c = t - 256;
        float a = fh_g[c] * r;
        ab_h[2 * c] = a; ab_h[2 * c + 1] = fh_be[c] - mu * a;
    }
}

// ---------------------------------------------------------------------------
// K4: blocks 0..2047 in-place BN+ReLU on m_frag; blocks 2048..2175 flow conv2.
// ---------------------------------------------------------------------------
__global__ void __launch_bounds__(256)
bnrelu_flow(unsigned short* __restrict__ m_frag, const float* __restrict__ ab,
            const float* __restrict__ hpre, const float* __restrict__ ab_h,
            const float* __restrict__ w2, const float* __restrict__ b2,
            float* __restrict__ flow8)
{
    __shared__ float s_ab[512];
    const int t = threadIdx.x;
    if (blockIdx.x < 2048) {
        s_ab[t] = ab[t]; s_ab[256 + t] = ab[256 + t];
        __syncthreads();
        const unsigned u = blockIdx.x * 256 + t;
        const int lg = (u >> 4) & 3, ks = (u >> 7) & 7;
        const int cb = ks * 32 + lg * 8;
        u16x8 v = *(const u16x8*)&m_frag[(size_t)u * 8];
        u16x8 o;
#pragma unroll
        for (int j = 0; j < 8; ++j) {
            float a = s_ab[2 * (cb + j)], b = s_ab[2 * (cb + j) + 1];
            o[j] = f2bf(fmaxf(a * bf2f(v[j]) + b, 0.f));
        }
        *(u16x8*)&m_frag[(size_t)u * 8] = o;
        return;
    }
    int idx = (blockIdx.x - 2048) * 256 + t;
    int w = idx & 63, h = (idx >> 6) & 63, co = (idx >> 12) & 1, n = idx >> 13;
    float acc = b2[co];
#pragma unroll
    for (int ci = 0; ci < 2; ++ci) {
        float a = ab_h[2 * ci], b = ab_h[2 * ci + 1];
        const float* p = hpre + (size_t)(n * 2 + ci) * HWSZ;
        const float* wp = &w2[(co * 2 + ci) * 9];
#pragma unroll
        for (int dy = 0; dy < 3; ++dy)
#pragma unroll
            for (int dx = 0; dx < 3; ++dx) {
                int gy = h + dy - 1, gx = w + dx - 1;
                float v = 0.f;
                if ((unsigned)gy < 64u && (unsigned)gx < 64u)
                    v = fmaxf(a * p[gy * 64 + gx] + b, 0.f);
                acc += wp[dy * 3 + dx] * v;
            }
    }
    flow8[idx] = acc * 8.0f;
}

// ---------------------------------------------------------------------------
// K5: fused 1x1-conv GEMM + bias + softmax(9) + convex upsample.
// Grid 1024 (XCD-swizzled: 16 uvt blocks sharing m_frag rows colocate per
// XCD), 512 thr, LDS 77.5KB -> 2 blocks/CU = 4 waves/SIMD.
// Wave = (row4, half2): q=2 px-groups, acc[9][2] (72 VGPR).
// ---------------------------------------------------------------------------
__global__ void __launch_bounds__(512, 4)
mask_combine_mfma(const unsigned short* __restrict__ m_frag,
                  const unsigned short* __restrict__ w2f,
                  const float* __restrict__ mk_b2,
                  const float* __restrict__ flow8,
                  float* __restrict__ out)
{
    __shared__ unsigned short s_w[36864];       // 73,728 B fragment order
    __shared__ float s_fl[2][6][66];            // 3,168 B
    __shared__ float s_bias[9][16];             // 576 B

    const int hw = blockIdx.x;
    const int xcd = hw & 7, slot = hw >> 3;
    const int lid = xcd * 128 + slot;
    const int uvt = lid & 15, hg = (lid >> 4) & 15, n = lid >> 8;

    const int tid = threadIdx.x;
    const int wv = tid >> 6, lane = tid & 63;
    const int lg = lane >> 4, ln = lane & 15;
    const int r_l = wv >> 1, half = wv & 1;
    const int h = hg * 4 + r_l;

    {
        const u16x8* wsrc = (const u16x8*)(w2f + (size_t)uvt * 36864);
        u16x8* wdst = (u16x8*)s_w;
        for (int i = tid; i < 4608; i += 512) wdst[i] = wsrc[i];
    }
    for (int i = tid; i < 2 * 6 * 66; i += 512) {
        int c = i / 396, rem = i - c * 396, r = rem / 66, col = rem - r * 66;
        int gy = hg * 4 - 1 + r, gx = col - 1;
        float v = 0.f;
        if ((unsigned)gy < 64u && (unsigned)gx < 64u)
            v = flow8[((size_t)(n * 2 + c)) * HWSZ + gy * 64 + gx];
        s_fl[c][r][col] = v;
    }
    if (tid < 144) s_bias[tid >> 4][tid & 15] = 0.25f * mk_b2[(tid >> 4) * 256 + uvt * 16 + (tid & 15)];
    __syncthreads();

    const unsigned short* wk0 = s_w + lg * 128 + ln * 8;
    const unsigned short* mb = m_frag + (size_t)(n * 256 + h * 4 + half * 2) * 4096 + lg * 128 + ln * 8;

    f32x4 acc[9][2];
#pragma unroll
    for (int k = 0; k < 9; ++k)
#pragma unroll
        for (int q = 0; q < 2; ++q) acc[k][q] = (f32x4){0.f, 0.f, 0.f, 0.f};

    s16x8 bq[2], bnx[2];
#pragma unroll
    for (int q = 0; q < 2; ++q) bq[q] = *(const s16x8*)&mb[q * 4096];
#pragma unroll
    for (int ks = 0; ks < 8; ++ks) {
        if (ks < 7) {
#pragma unroll
            for (int q = 0; q < 2; ++q) bnx[q] = *(const s16x8*)&mb[q * 4096 + (ks + 1) * 512];
        }
        const unsigned short* wk = wk0 + ks * 512;
#pragma unroll
        for (int k = 0; k < 9; ++k) {
            s16x8 af = *(const s16x8*)&wk[k * 4096];
#pragma unroll
            for (int q = 0; q < 2; ++q)
                acc[k][q] = __builtin_amdgcn_mfma_f32_16x16x32_bf16(af, bq[q], acc[k][q], 0, 0, 0);
        }
#pragma unroll
        for (int q = 0; q < 2; ++q) bq[q] = bnx[q];
    }

    // epilogue: softmax over k + convex combine + coalesced float4 stores
#pragma unroll
    for (int q = 0; q < 2; ++q) {
        const int w = half * 32 + q * 16 + ln;
        float o0[4], o1[4];
#pragma unroll
        for (int r = 0; r < 4; ++r) {
            const int vv = lg * 4 + r;
            float p[9], mx = -1e30f;
#pragma unroll
            for (int k = 0; k < 9; ++k) {
                p[k] = acc[k][q][r] + s_bias[k][vv];
                mx = fmaxf(mx, p[k]);
            }
            float sum = 0.f;
#pragma unroll
            for (int k = 0; k < 9; ++k) { p[k] = __expf(p[k] - mx); sum += p[k]; }
            float inv = 1.0f / sum;
            float a0 = 0.f, a1 = 0.f;
#pragma unroll
            for (int k = 0; k < 9; ++k) {
                const int dy = k / 3, dx = k % 3;
                a0 += p[k] * s_fl[0][r_l + dy][w + dx];
                a1 += p[k] * s_fl[1][r_l + dy][w + dx];
            }
            o0[r] = a0 * inv; o1[r] = a1 * inv;
        }
        float* base0 = out + ((size_t)(n * 2 + 0) * 1024 + h * 16 + uvt) * 1024 + w * 16 + lg * 4;
        float* base1 = out + ((size_t)(n * 2 + 1) * 1024 + h * 16 + uvt) * 1024 + w * 16 + lg * 4;
        *(f32x4*)base0 = (f32x4){o0[0], o0[1], o0[2], o0[3]};
        *(f32x4*)base1 = (f32x4){o1[0], o1[1], o1[2], o1[3]};
    }
}

// ---------------------------------------------------------------------------
extern "C" void kernel_launch(void* const* d_in, const int* in_sizes, int n_in,
                              void* d_out, int out_size, void* d_ws, size_t ws_size,
                              hipStream_t stream) {
    const float* img   = (const float*)d_in[0];
    const float* fh_w1 = (const float*)d_in[1];
    const float* fh_b1 = (const float*)d_in[2];
    const float* fh_g  = (const float*)d_in[3];
    const float* fh_be = (const float*)d_in[4];
    const float* fh_w2 = (const float*)d_in[5];
    const float* fh_b2 = (const float*)d_in[6];
    const float* mk_w1 = (const float*)d_in[7];
    const float* mk_b1 = (const float*)d_in[8];
    const float* mk_g  = (const float*)d_in[9];
    const float* mk_be = (const float*)d_in[10];
    const float* mk_w2 = (const float*)d_in[11];
    const float* mk_b2 = (const float*)d_in[12];
    float* out = (float*)d_out;

    char* p = (char*)d_ws;
    unsigned short* w2f    = (unsigned short*)p;  p += (size_t)1179648;
    unsigned short* w1f    = (unsigned short*)p;  p += (size_t)663552;
    unsigned short* imgT   = (unsigned short*)p;  p += (size_t)4194304;
    unsigned short* m_frag = (unsigned short*)p;  p += (size_t)8388608;
    float* h_pre  = (float*)p;  p += (size_t)131072;
    float* flow8  = (float*)p;  p += (size_t)131072;
    float* ps_s   = (float*)p;  p += (size_t)280576;
    float* ps_s2  = (float*)p;  p += (size_t)280576;
    float* ab_m   = (float*)p;  p += 2048;
    float* ab_h   = (float*)p;  p += 64;

    prep_all<<<2560, 256, 0, stream>>>(img, mk_w1, fh_w1, mk_w2, imgT, w1f, w2f);
    conv1_mfma<<<512, 512, 0, stream>>>(imgT, w1f, mk_b1, fh_b1, m_frag, h_pre, ps_s, ps_s2);
    bn_final2<<<1, 320, 0, stream>>>(ps_s, ps_s2, mk_g, mk_be, fh_g, fh_be, ab_m, ab_h);
    bnrelu_flow<<<2176, 256, 0, stream>>>(m_frag, ab_m, h_pre, ab_h, fh_w2, fh_b2, flow8);
    mask_combine_mfma<<<1024, 512, 0, stream>>>(m_frag, w2f, mk_b2, flow8, out);
}